// Round 1
// baseline (177.106 us; speedup 1.0000x reference)
//
#include <hip/hip_runtime.h>
#include <math.h>

#define NB 64
#define NP 784      // 28*28
#define ND 512
#define NK 64
#define EPS_F 1e-12f

// ---------------------------------------------------------------------------
// Kernel 1: s = x . W + bias ; a = softmax_k(s) ; a_sum[b,k] += sum_n a
// grid (ceil(784/64)=13, 64 batches), block 256
// 64x64 output tile (pixels x clusters), K-loop over D in 64-chunks.
// ---------------------------------------------------------------------------
__global__ __launch_bounds__(256) void k_assign(
    const float* __restrict__ x, const float* __restrict__ Wm,
    const float* __restrict__ bias, float* __restrict__ a,
    float* __restrict__ a_sum)
{
    __shared__ float xs[64][68];   // [pixel][d]
    __shared__ float wt[64][68];   // [d][k]
    __shared__ float asum_l[64];

    const int t  = threadIdx.x;
    const int tx = t & 15;         // cluster group (4 k's)
    const int ty = t >> 4;         // pixel group  (4 pixels)
    const int b  = blockIdx.y;
    const int n0 = blockIdx.x * 64;

    if (t < 64) asum_l[t] = 0.0f;

    const float* xb = x + (size_t)b * NP * ND;
    float acc[4][4] = {};

    for (int d0 = 0; d0 < ND; d0 += 64) {
        __syncthreads();
#pragma unroll
        for (int i = 0; i < 4; ++i) {
            int f = (i * 256 + t) * 4;      // flat float index 0..4095, step 4
            int row = f >> 6, col = f & 63;
            float4 w4 = *(const float4*)(Wm + (size_t)(d0 + row) * NK + col);
            *(float4*)&wt[row][col] = w4;
            int n = n0 + row;
            float4 x4 = make_float4(0.f, 0.f, 0.f, 0.f);
            if (n < NP) x4 = *(const float4*)(xb + (size_t)n * ND + d0 + col);
            *(float4*)&xs[row][col] = x4;
        }
        __syncthreads();
#pragma unroll 8
        for (int dd = 0; dd < 64; ++dd) {
            float4 w4 = *(const float4*)&wt[dd][tx * 4];
            float wv[4] = {w4.x, w4.y, w4.z, w4.w};
            float xv[4];
#pragma unroll
            for (int i = 0; i < 4; ++i) xv[i] = xs[ty * 4 + i][dd];
#pragma unroll
            for (int i = 0; i < 4; ++i)
#pragma unroll
                for (int j = 0; j < 4; ++j)
                    acc[i][j] = fmaf(xv[i], wv[j], acc[i][j]);
        }
    }

    // bias + softmax over k (64 clusters spread across 16 tx-lanes x 4 regs)
    float4 b4 = *(const float4*)(bias + tx * 4);
    float bv[4] = {b4.x, b4.y, b4.z, b4.w};
    float part[4] = {0.f, 0.f, 0.f, 0.f};

#pragma unroll
    for (int i = 0; i < 4; ++i) {
        int n = n0 + ty * 4 + i;
        float s[4];
        float m = -1e30f;
#pragma unroll
        for (int j = 0; j < 4; ++j) { s[j] = acc[i][j] + bv[j]; m = fmaxf(m, s[j]); }
#pragma unroll
        for (int mask = 1; mask < 16; mask <<= 1)
            m = fmaxf(m, __shfl_xor(m, mask, 64));
        float sum = 0.f;
#pragma unroll
        for (int j = 0; j < 4; ++j) { s[j] = __expf(s[j] - m); sum += s[j]; }
#pragma unroll
        for (int mask = 1; mask < 16; mask <<= 1)
            sum += __shfl_xor(sum, mask, 64);
        float r = 1.0f / sum;
#pragma unroll
        for (int j = 0; j < 4; ++j) s[j] *= r;
        if (n < NP) {
            *(float4*)(a + ((size_t)b * NP + n) * NK + tx * 4) =
                make_float4(s[0], s[1], s[2], s[3]);
#pragma unroll
            for (int j = 0; j < 4; ++j) part[j] += s[j];
        }
    }
#pragma unroll
    for (int j = 0; j < 4; ++j) atomicAdd(&asum_l[tx * 4 + j], part[j]);
    __syncthreads();
    if (t < 64) atomicAdd(&a_sum[b * NK + t], asum_l[t]);
}

// ---------------------------------------------------------------------------
// Kernel 2: v[b,d,k] = sum_n a[b,n,k] * x[b,n,d] + C[d,k] * a_sum[b,k]
// grid (512/64=8 d-tiles, 64 batches), block 256, 64x64 (d x k) tile.
// ---------------------------------------------------------------------------
__global__ __launch_bounds__(256) void k_vacc(
    const float* __restrict__ x, const float* __restrict__ a,
    const float* __restrict__ Cm, const float* __restrict__ a_sum,
    float* __restrict__ v)
{
    __shared__ float xs[64][68];   // [n][d]
    __shared__ float at[64][68];   // [n][k]

    const int t  = threadIdx.x;
    const int tx = t & 15;         // k group
    const int ty = t >> 4;         // d group
    const int b  = blockIdx.y;
    const int d0 = blockIdx.x * 64;

    const float* xb = x + (size_t)b * NP * ND;
    const float* ab = a + (size_t)b * NP * NK;
    float acc[4][4] = {};

    for (int n0 = 0; n0 < NP; n0 += 64) {
        __syncthreads();
#pragma unroll
        for (int i = 0; i < 4; ++i) {
            int f = (i * 256 + t) * 4;
            int row = f >> 6, col = f & 63;
            int n = n0 + row;
            float4 x4 = make_float4(0.f, 0.f, 0.f, 0.f);
            float4 a4 = make_float4(0.f, 0.f, 0.f, 0.f);
            if (n < NP) {
                x4 = *(const float4*)(xb + (size_t)n * ND + d0 + col);
                a4 = *(const float4*)(ab + (size_t)n * NK + col);
            }
            *(float4*)&xs[row][col] = x4;
            *(float4*)&at[row][col] = a4;
        }
        __syncthreads();
#pragma unroll 8
        for (int nn = 0; nn < 64; ++nn) {
            float4 x4 = *(const float4*)&xs[nn][ty * 4];
            float4 a4 = *(const float4*)&at[nn][tx * 4];
            float xv[4] = {x4.x, x4.y, x4.z, x4.w};
            float av[4] = {a4.x, a4.y, a4.z, a4.w};
#pragma unroll
            for (int i = 0; i < 4; ++i)
#pragma unroll
                for (int j = 0; j < 4; ++j)
                    acc[i][j] = fmaf(xv[i], av[j], acc[i][j]);
        }
    }

    float4 s4 = *(const float4*)(a_sum + b * NK + tx * 4);
    float sv[4] = {s4.x, s4.y, s4.z, s4.w};
#pragma unroll
    for (int i = 0; i < 4; ++i) {
        int d = d0 + ty * 4 + i;
        float4 c4 = *(const float4*)(Cm + (size_t)d * NK + tx * 4);
        float4 o;
        o.x = acc[i][0] + c4.x * sv[0];
        o.y = acc[i][1] + c4.y * sv[1];
        o.z = acc[i][2] + c4.z * sv[2];
        o.w = acc[i][3] + c4.w * sv[3];
        *(float4*)(v + ((size_t)b * ND + d) * NK + tx * 4) = o;
    }
}

// ---------------------------------------------------------------------------
// Kernel 3: intra-normalize over D per (b,k), then global L2 per b.
// out[b, d*64+k] = v / (sqrt(ss_k+eps) * sqrt(sum_k ss_k/(ss_k+eps) + eps))
// grid 64, block 256. thread: k = t&63, d-stripe = t>>6.
// ---------------------------------------------------------------------------
__global__ __launch_bounds__(256) void k_norm(
    const float* __restrict__ v, float* __restrict__ out)
{
    __shared__ float ssl[4][64];
    __shared__ float scl[64];
    const int t = threadIdx.x;
    const int k = t & 63, dg = t >> 6;
    const int b = blockIdx.x;
    const float* vb = v + (size_t)b * ND * NK;

    float ss = 0.f;
    for (int d = dg; d < ND; d += 4) {
        float val = vb[d * NK + k];
        ss = fmaf(val, val, ss);
    }
    ssl[dg][k] = ss;
    __syncthreads();
    if (t < 64) {
        float tot = ssl[0][t] + ssl[1][t] + ssl[2][t] + ssl[3][t];
        float c = tot / (tot + EPS_F);   // squared norm of intra-normalized col
        float g = c;
#pragma unroll
        for (int mask = 1; mask < 64; mask <<= 1)
            g += __shfl_xor(g, mask, 64);
        scl[t] = 1.0f / (sqrtf(tot + EPS_F) * sqrtf(g + EPS_F));
    }
    __syncthreads();
    float* ob = out + (size_t)b * ND * NK;
    for (int d = dg; d < ND; d += 4)
        ob[d * NK + k] = vb[d * NK + k] * scl[k];
}

// ---------------------------------------------------------------------------
extern "C" void kernel_launch(void* const* d_in, const int* in_sizes, int n_in,
                              void* d_out, int out_size, void* d_ws, size_t ws_size,
                              hipStream_t stream)
{
    const float* x    = (const float*)d_in[0];
    const float* Wm   = (const float*)d_in[1];
    const float* bias = (const float*)d_in[2];
    const float* Cm   = (const float*)d_in[3];
    float* out = (float*)d_out;

    float* ws    = (float*)d_ws;
    float* a     = ws;                               // 64*784*64 floats
    float* a_sum = a + (size_t)NB * NP * NK;         // 64*64
    float* v     = a_sum + NB * NK;                  // 64*512*64

    hipMemsetAsync(a_sum, 0, NB * NK * sizeof(float), stream);

    dim3 g1((NP + 63) / 64, NB);
    hipLaunchKernelGGL(k_assign, g1, dim3(256), 0, stream, x, Wm, bias, a, a_sum);
    dim3 g2(ND / 64, NB);
    hipLaunchKernelGGL(k_vacc, g2, dim3(256), 0, stream, x, a, Cm, a_sum, v);
    hipLaunchKernelGGL(k_norm, dim3(NB), dim3(256), 0, stream, v, out);
}

// Round 2
// 109.834 us; speedup vs baseline: 1.6125x; 1.6125x over previous
//
#include <hip/hip_runtime.h>
#include <math.h>

#define NB 64
#define NP 784      // 28*28
#define ND 512
#define NK 64
#define EPS_F 1e-12f

typedef float f32x4 __attribute__((ext_vector_type(4)));
typedef short bf16x8 __attribute__((ext_vector_type(8)));
typedef unsigned long long u64;

__device__ __forceinline__ unsigned short f2bf(float f) {
    unsigned u = __builtin_bit_cast(unsigned, f);
    u += 0x7fffu + ((u >> 16) & 1u);
    return (unsigned short)(u >> 16);
}

// 16B MFMA fragment read from a [64 rows][64 bf16] LDS tile (128B rows),
// XOR-swizzled: byte_off_in_row ^= (row&7)<<4  (T2 / G4 pattern).
__device__ __forceinline__ bf16x8 ldfrag(const unsigned short* base, int row, int off) {
    return *(const bf16x8*)((const char*)base + row * 128 + (off ^ ((row & 7) << 4)));
}

// ---------------------------------------------------------------------------
// K0: Wt[k][d] (bf16) = W[d][k] (fp32).  32768 elems.
// ---------------------------------------------------------------------------
__global__ __launch_bounds__(256) void k_wt(const float* __restrict__ W,
                                            unsigned short* __restrict__ Wt)
{
    int idx = blockIdx.x * 256 + threadIdx.x;   // 0..32767
    int d = idx >> 6, k = idx & 63;
    Wt[(size_t)k * ND + d] = f2bf(W[idx]);
}

// ---------------------------------------------------------------------------
// K1: s = x.W + bias ; a = softmax_k(s) ; aT[b][k][n] (bf16) ; a_sum[b][k]
// grid (13, 64), 256 threads (4 waves). Tile: 64 pixels x 64 clusters.
// MFMA 16x16x32 bf16: M=n, N=k, Kdim=d. Wave w owns n-rows w*16..w*16+15.
// ---------------------------------------------------------------------------
__global__ __launch_bounds__(256) void k_assign(
    const float* __restrict__ x, const unsigned short* __restrict__ Wt,
    const float* __restrict__ bias, unsigned short* __restrict__ aT,
    float* __restrict__ a_sum)
{
    __shared__ unsigned short lx[4096];   // [n][d] bf16, swizzled
    __shared__ unsigned short lw[4096];   // [k][d] bf16, swizzled
    __shared__ float asum_l[64];

    const int t  = threadIdx.x;
    const int w  = t >> 6;        // wave
    const int l  = t & 63;
    const int lr = l & 15;
    const int lg = l >> 4;
    const int b  = blockIdx.y;
    const int n0 = blockIdx.x * 64;

    if (t < 64) asum_l[t] = 0.0f;

    const float* xb = x + (size_t)b * NP * ND;
    f32x4 acc[4] = {};   // [k-frag][4 regs]

    for (int d0 = 0; d0 < ND; d0 += 64) {
        __syncthreads();
        // stage x tile [64 n][64 d] fp32 -> bf16
#pragma unroll
        for (int i = 0; i < 4; ++i) {
            int nloc = (t >> 4) + i * 16;
            int dloc = (t & 15) * 4;
            float4 f4 = make_float4(0.f, 0.f, 0.f, 0.f);
            if (n0 + nloc < NP)
                f4 = *(const float4*)(xb + (size_t)(n0 + nloc) * ND + d0 + dloc);
            u64 pk = (u64)f2bf(f4.x) | ((u64)f2bf(f4.y) << 16) |
                     ((u64)f2bf(f4.z) << 32) | ((u64)f2bf(f4.w) << 48);
            *(u64*)((char*)lx + nloc * 128 + ((dloc * 2) ^ ((nloc & 7) << 4))) = pk;
        }
        // stage Wt tile [64 k][64 d] bf16 (16B copies)
#pragma unroll
        for (int i = 0; i < 2; ++i) {
            int k   = (t >> 3) + i * 32;
            int d8  = (t & 7) * 8;
            int4 v4 = *(const int4*)(Wt + (size_t)k * ND + d0 + d8);
            *(int4*)((char*)lw + k * 128 + ((d8 * 2) ^ ((k & 7) << 4))) = v4;
        }
        __syncthreads();
#pragma unroll
        for (int kk = 0; kk < 2; ++kk) {
            bf16x8 af = ldfrag(lx, w * 16 + lr, lg * 16 + kk * 64);
#pragma unroll
            for (int f = 0; f < 4; ++f) {
                bf16x8 bfr = ldfrag(lw, f * 16 + lr, lg * 16 + kk * 64);
                acc[f] = __builtin_amdgcn_mfma_f32_16x16x32_bf16(af, bfr, acc[f], 0, 0, 0);
            }
        }
    }

    // ---- softmax over k. Lane holds k = f*16+lr (4 frags), n = n0+w*16+lg*4+r.
    float pv[4][4];               // [f][r]
    float part[4] = {0.f, 0.f, 0.f, 0.f};
    float bv[4];
#pragma unroll
    for (int f = 0; f < 4; ++f) bv[f] = bias[f * 16 + lr];

#pragma unroll
    for (int r = 0; r < 4; ++r) {
        int n = n0 + w * 16 + lg * 4 + r;
        float sv[4];
        float m = -1e30f;
#pragma unroll
        for (int f = 0; f < 4; ++f) { sv[f] = acc[f][r] + bv[f]; m = fmaxf(m, sv[f]); }
#pragma unroll
        for (int mask = 1; mask < 16; mask <<= 1)
            m = fmaxf(m, __shfl_xor(m, mask, 64));
        float sum = 0.f;
#pragma unroll
        for (int f = 0; f < 4; ++f) { sv[f] = __expf(sv[f] - m); sum += sv[f]; }
#pragma unroll
        for (int mask = 1; mask < 16; mask <<= 1)
            sum += __shfl_xor(sum, mask, 64);
        float inv = 1.0f / sum;
        bool valid = (n < NP);
#pragma unroll
        for (int f = 0; f < 4; ++f) {
            pv[f][r] = sv[f] * inv;
            if (valid) part[f] += pv[f][r];
        }
    }

    // a_sum partials (fp32, pre-rounding)
#pragma unroll
    for (int f = 0; f < 4; ++f) atomicAdd(&asum_l[f * 16 + lr], part[f]);

    // ---- bounce a into lx as [k][n] bf16 (paired regs -> b32 writes)
    __syncthreads();   // everyone done reading lx/lw
    {
        int nl0 = w * 16 + lg * 4;
#pragma unroll
        for (int f = 0; f < 4; ++f) {
            int krow = f * 16 + lr;
#pragma unroll
            for (int rp = 0; rp < 2; ++rp) {
                unsigned v32 = (unsigned)f2bf(pv[f][2 * rp]) |
                               ((unsigned)f2bf(pv[f][2 * rp + 1]) << 16);
                *(unsigned*)((char*)lx + krow * 128 +
                             ((nl0 * 2 + rp * 4) ^ ((krow & 7) << 4))) = v32;
            }
        }
    }
    __syncthreads();
    // coalesced store aT[b][k][n0..n0+63]
    for (int r2 = (t >> 3); r2 < 64; r2 += 32) {
        int n8 = (t & 7) * 8;
        if (n0 + n8 < NP) {
            int4 val = *(const int4*)((const char*)lx + r2 * 128 +
                                      ((n8 * 2) ^ ((r2 & 7) << 4)));
            *(int4*)(aT + ((size_t)b * NK + r2) * NP + n0 + n8) = val;
        }
    }
    if (t < 64) atomicAdd(&a_sum[b * NK + t], asum_l[t]);
}

// ---------------------------------------------------------------------------
// K2: v[b][d][k] = sum_n x[b][n][d]*a[b][n][k] + C[d][k]*a_sum[b][k]
// grid (8, 64), 256 threads. MFMA: M=k(64), N=d(64-tile), Kdim=n.
// A = aT rows (k-major, n contiguous). B = x^T staged (transpose+convert).
// ---------------------------------------------------------------------------
__global__ __launch_bounds__(256) void k_vlad(
    const float* __restrict__ x, const unsigned short* __restrict__ aT,
    const float* __restrict__ Cm, const float* __restrict__ a_sum,
    float* __restrict__ v)
{
    __shared__ unsigned short la[4096];    // [k][n] bf16, swizzled
    __shared__ unsigned short lxT[4096];   // [d][n] bf16, swizzled

    const int t  = threadIdx.x;
    const int w  = t >> 6;
    const int l  = t & 63;
    const int lr = l & 15;
    const int lg = l >> 4;
    const int b  = blockIdx.y;
    const int d0 = blockIdx.x * 64;

    const float* xb = x + (size_t)b * NP * ND;
    const unsigned short* ab = aT + (size_t)b * NK * NP;
    f32x4 acc[4] = {};   // [d-frag][4 regs]

    for (int n0 = 0; n0 < NP; n0 += 64) {
        __syncthreads();
        // stage aT tile [64 k][64 n] (16B copies, zero-fill tail)
#pragma unroll
        for (int i = 0; i < 2; ++i) {
            int k  = (t >> 3) + i * 32;
            int n8 = (t & 7) * 8;
            int4 val = make_int4(0, 0, 0, 0);
            if (n0 + n8 < NP)
                val = *(const int4*)(ab + (size_t)k * NP + n0 + n8);
            *(int4*)((char*)la + k * 128 + ((n8 * 2) ^ ((k & 7) << 4))) = val;
        }
        // stage x^T tile [64 d][64 n]: units of 2d x 4n
        {
            int dp = t & 31;                  // d pair -> d = 2*dp, 2*dp+1
#pragma unroll
            for (int i = 0; i < 2; ++i) {
                int q = (t >> 5) + i * 8;     // n quad -> n = 4*q..4*q+3
                float xv[4][2];
#pragma unroll
                for (int j = 0; j < 4; ++j) {
                    int n = n0 + q * 4 + j;
                    float2 f2 = make_float2(0.f, 0.f);
                    if (n < NP)
                        f2 = *(const float2*)(xb + (size_t)n * ND + d0 + dp * 2);
                    xv[j][0] = f2.x; xv[j][1] = f2.y;
                }
#pragma unroll
                for (int jd = 0; jd < 2; ++jd) {
                    int dr = dp * 2 + jd;
                    u64 pk = (u64)f2bf(xv[0][jd]) | ((u64)f2bf(xv[1][jd]) << 16) |
                             ((u64)f2bf(xv[2][jd]) << 32) | ((u64)f2bf(xv[3][jd]) << 48);
                    *(u64*)((char*)lxT + dr * 128 + ((q * 8) ^ ((dr & 7) << 4))) = pk;
                }
            }
        }
        __syncthreads();
#pragma unroll
        for (int kk = 0; kk < 2; ++kk) {
            bf16x8 af = ldfrag(la, w * 16 + lr, lg * 16 + kk * 64);
#pragma unroll
            for (int f = 0; f < 4; ++f) {
                bf16x8 bfr = ldfrag(lxT, f * 16 + lr, lg * 16 + kk * 64);
                acc[f] = __builtin_amdgcn_mfma_f32_16x16x32_bf16(af, bfr, acc[f], 0, 0, 0);
            }
        }
    }

    // epilogue: lane: k = w*16+lg*4+r (regs = consecutive k), d = d0+f*16+lr
    int k0 = w * 16 + lg * 4;
    f32x4 s4 = *(const f32x4*)(a_sum + b * NK + k0);
#pragma unroll
    for (int f = 0; f < 4; ++f) {
        int d = d0 + f * 16 + lr;
        f32x4 c4 = *(const f32x4*)(Cm + (size_t)d * NK + k0);
        f32x4 o  = acc[f] + c4 * s4;
        *(f32x4*)(v + ((size_t)b * ND + d) * NK + k0) = o;
    }
}

// ---------------------------------------------------------------------------
// K3: intra-normalize over D per (b,k), then global L2 per b.
// ---------------------------------------------------------------------------
__global__ __launch_bounds__(256) void k_norm(
    const float* __restrict__ v, float* __restrict__ out)
{
    __shared__ float ssl[4][64];
    __shared__ float scl[64];
    const int t = threadIdx.x;
    const int k = t & 63, dg = t >> 6;
    const int b = blockIdx.x;
    const float* vb = v + (size_t)b * ND * NK;

    float ss = 0.f;
    for (int d = dg; d < ND; d += 4) {
        float val = vb[d * NK + k];
        ss = fmaf(val, val, ss);
    }
    ssl[dg][k] = ss;
    __syncthreads();
    if (t < 64) {
        float tot = ssl[0][t] + ssl[1][t] + ssl[2][t] + ssl[3][t];
        float c = tot / (tot + EPS_F);
        float g = c;
#pragma unroll
        for (int mask = 1; mask < 64; mask <<= 1)
            g += __shfl_xor(g, mask, 64);
        scl[t] = 1.0f / (sqrtf(tot + EPS_F) * sqrtf(g + EPS_F));
    }
    __syncthreads();
    float* ob = out + (size_t)b * ND * NK;
    for (int d = dg; d < ND; d += 4)
        ob[d * NK + k] = vb[d * NK + k] * scl[k];
}

// ---------------------------------------------------------------------------
extern "C" void kernel_launch(void* const* d_in, const int* in_sizes, int n_in,
                              void* d_out, int out_size, void* d_ws, size_t ws_size,
                              hipStream_t stream)
{
    const float* x    = (const float*)d_in[0];
    const float* Wm   = (const float*)d_in[1];
    const float* bias = (const float*)d_in[2];
    const float* Cm   = (const float*)d_in[3];
    float* out = (float*)d_out;

    // workspace layout (bytes)
    char* ws = (char*)d_ws;
    unsigned short* aT = (unsigned short*)ws;                       // 64*64*784*2 = 6,422,528
    char* p = ws + (size_t)NB * NK * NP * 2;
    float* a_sum = (float*)p;                                       // 64*64*4 = 16,384
    p += (size_t)NB * NK * 4;
    float* v = (float*)p;                                           // 64*512*64*4 = 8,388,608
    p += (size_t)NB * ND * NK * 4;
    unsigned short* Wt = (unsigned short*)p;                        // 64*512*2 = 65,536

    hipMemsetAsync(a_sum, 0, NB * NK * sizeof(float), stream);
    hipLaunchKernelGGL(k_wt, dim3(128), dim3(256), 0, stream, Wm, Wt);

    dim3 g1((NP + 63) / 64, NB);
    hipLaunchKernelGGL(k_assign, g1, dim3(256), 0, stream, x, Wt, bias, aT, a_sum);
    dim3 g2(ND / 64, NB);
    hipLaunchKernelGGL(k_vlad, g2, dim3(256), 0, stream, x, aT, Cm, a_sum, v);
    hipLaunchKernelGGL(k_norm, dim3(NB), dim3(256), 0, stream, v, out);
}

// Round 3
// 107.623 us; speedup vs baseline: 1.6456x; 1.0205x over previous
//
#include <hip/hip_runtime.h>
#include <math.h>

#define NB 64
#define NP 784      // 28*28
#define ND 512
#define NK 64
#define EPS_F 1e-12f

typedef float f32x4 __attribute__((ext_vector_type(4)));
typedef short bf16x8 __attribute__((ext_vector_type(8)));

__device__ __forceinline__ unsigned short f2bf(float f) {
    unsigned u = __builtin_bit_cast(unsigned, f);
    u += 0x7fffu + ((u >> 16) & 1u);
    return (unsigned short)(u >> 16);
}

__device__ __forceinline__ bf16x8 pack8(const float* s) {
    bf16x8 r;
#pragma unroll
    for (int i = 0; i < 8; ++i) r[i] = (short)f2bf(s[i]);
    return r;
}

// ---------------------------------------------------------------------------
// K0: Wt[k][d] (bf16) = W[d][k] (fp32); also zero a_sum (replaces memset).
// ---------------------------------------------------------------------------
__global__ __launch_bounds__(256) void k_wt(const float* __restrict__ W,
                                            unsigned short* __restrict__ Wt,
                                            float* __restrict__ a_sum)
{
    int idx = blockIdx.x * 256 + threadIdx.x;   // 0..32767
    int k = idx >> 9, d = idx & 511;
    Wt[idx] = f2bf(W[(size_t)d * NK + k]);
    if (idx < NB * NK) a_sum[idx] = 0.f;
}

// ---------------------------------------------------------------------------
// K1: s = x.W + bias ; a = softmax_k(s) ; aT[b][k][n] bf16 ; a_sum[b][k]
// grid (13, 64), 256 threads (4 waves). Tile 64n x 64k.
// Main loop: NO LDS, NO barriers. A-frags (x) direct from HBM (8 contiguous
// d per lane -> 2 float4 + convert). B-frags (Wt, 64KB, L2-resident) direct
// from global (16B contiguous). Compiler pipelines the 16 unrolled steps.
// ---------------------------------------------------------------------------
__global__ __launch_bounds__(256) void k_assign(
    const float* __restrict__ x, const unsigned short* __restrict__ Wt,
    const float* __restrict__ bias, unsigned short* __restrict__ aT,
    float* __restrict__ a_sum)
{
    __shared__ unsigned short lb[4096];   // bounce [64k][64n] bf16, swizzled
    __shared__ float asum_l[64];

    const int t = threadIdx.x;
    const int w = t >> 6, l = t & 63, lr = l & 15, lg = l >> 4;
    const int b = blockIdx.y, n0 = blockIdx.x * 64;
    if (t < 64) asum_l[t] = 0.f;

    const float* xb = x + (size_t)b * NP * ND;
    const int na = n0 + w * 16 + lr;           // A-row this lane loads
    const bool aok = (na < NP);
    const float* xrow = xb + (size_t)na * ND;
    f32x4 acc[4] = {};                          // [kf], C: k=kf*16+lr? no: see below

#pragma unroll
    for (int d0 = 0; d0 < ND; d0 += 32) {       // 16 steps, K=32 each
        const int dbase = d0 + lg * 8;          // lane's 8 K-slots
        bf16x8 af = {};
        if (aok) {
            float xv[8];
            *(float4*)&xv[0] = *(const float4*)(xrow + dbase);
            *(float4*)&xv[4] = *(const float4*)(xrow + dbase + 4);
            af = pack8(xv);
        }
#pragma unroll
        for (int kf = 0; kf < 4; ++kf) {
            bf16x8 bfr = *(const bf16x8*)(Wt + (size_t)(kf * 16 + lr) * ND + dbase);
            acc[kf] = __builtin_amdgcn_mfma_f32_16x16x32_bf16(af, bfr, acc[kf], 0, 0, 0);
        }
    }

    // softmax over k: lane holds k = kf*16+lr, n = n0 + w*16 + lg*4 + r
    float pv[4][4];
    float part[4] = {0.f, 0.f, 0.f, 0.f};
    float bv[4];
#pragma unroll
    for (int kf = 0; kf < 4; ++kf) bv[kf] = bias[kf * 16 + lr];

#pragma unroll
    for (int r = 0; r < 4; ++r) {
        int n = n0 + w * 16 + lg * 4 + r;
        float sv[4];
        float m = -1e30f;
#pragma unroll
        for (int kf = 0; kf < 4; ++kf) { sv[kf] = acc[kf][r] + bv[kf]; m = fmaxf(m, sv[kf]); }
#pragma unroll
        for (int mask = 1; mask < 16; mask <<= 1)
            m = fmaxf(m, __shfl_xor(m, mask, 64));
        float sum = 0.f;
#pragma unroll
        for (int kf = 0; kf < 4; ++kf) { sv[kf] = __expf(sv[kf] - m); sum += sv[kf]; }
#pragma unroll
        for (int mask = 1; mask < 16; mask <<= 1)
            sum += __shfl_xor(sum, mask, 64);
        float inv = 1.0f / sum;
        bool valid = (n < NP);
#pragma unroll
        for (int kf = 0; kf < 4; ++kf) {
            pv[kf][r] = sv[kf] * inv;
            if (valid) part[kf] += pv[kf][r];
        }
    }
#pragma unroll
    for (int kf = 0; kf < 4; ++kf) atomicAdd(&asum_l[kf * 16 + lr], part[kf]);

    // bounce a -> [k][n] bf16 in LDS (waves write disjoint column granules)
    const int nl0 = w * 16 + lg * 4;
#pragma unroll
    for (int kf = 0; kf < 4; ++kf) {
        int krow = kf * 16 + lr;
#pragma unroll
        for (int rp = 0; rp < 2; ++rp) {
            unsigned v32 = (unsigned)f2bf(pv[kf][2 * rp]) |
                           ((unsigned)f2bf(pv[kf][2 * rp + 1]) << 16);
            *(unsigned*)((char*)lb + krow * 128 +
                         ((nl0 * 2 + rp * 4) ^ ((krow & 7) << 4))) = v32;
        }
    }
    __syncthreads();
    // coalesced store aT[b][k][n0..n0+63]
    for (int r2 = (t >> 3); r2 < 64; r2 += 32) {
        int n8 = (t & 7) * 8;
        if (n0 + n8 < NP) {
            int4 val = *(const int4*)((const char*)lb + r2 * 128 +
                                      ((n8 * 2) ^ ((r2 & 7) << 4)));
            *(int4*)(aT + ((size_t)b * NK + r2) * NP + n0 + n8) = val;
        }
    }
    if (t < 64) atomicAdd(&a_sum[b * NK + t], asum_l[t]);
}

// ---------------------------------------------------------------------------
// K2: v[b][d][k] = sum_n x[b][n][d]*a[b][n][k] + C[d][k]*a_sum[b][k]
// grid (8, 64), 256 threads. NO barriers. A = aT rows direct from global
// (L2-resident). B = x^T staged per-wave-private (double-buffered 2KB,
// swizzled). MFMA: M=k (4 frags), N=d (wave owns 16 d-cols), Kdim=n.
// ---------------------------------------------------------------------------
__global__ __launch_bounds__(256) void k_vlad(
    const float* __restrict__ x, const unsigned short* __restrict__ aT,
    const float* __restrict__ Cm, const float* __restrict__ a_sum,
    float* __restrict__ v)
{
    __shared__ unsigned short lxT[8][1024];   // [wave*2+buf][16d x 64n] swizzled

    const int t = threadIdx.x;
    const int w = t >> 6, l = t & 63, lr = l & 15, lg = l >> 4;
    const int b = blockIdx.y, d0 = blockIdx.x * 64;
    const int np_ = l & 31, dq = l >> 5;

    const float* xb = x + (size_t)b * NP * ND;
    const unsigned short* ab = aT + (size_t)b * NK * NP;
    const float* xcol = xb + d0 + w * 16 + dq * 8;   // lane's 8 d-columns
    f32x4 acc[4] = {};

#pragma unroll
    for (int it = 0; it < 13; ++it) {
        const int n0 = it * 64;
        unsigned short* lt = lxT[w * 2 + (it & 1)];
        // ---- stage wave-private x^T sub-tile [16 d][64 n] (fp32->bf16)
        const int nlo = n0 + 2 * np_;
        float r0[8] = {}, r1[8] = {};
        if (nlo < NP) {
            *(float4*)&r0[0] = *(const float4*)(xcol + (size_t)nlo * ND);
            *(float4*)&r0[4] = *(const float4*)(xcol + (size_t)nlo * ND + 4);
        }
        if (nlo + 1 < NP) {
            *(float4*)&r1[0] = *(const float4*)(xcol + (size_t)(nlo + 1) * ND);
            *(float4*)&r1[4] = *(const float4*)(xcol + (size_t)(nlo + 1) * ND + 4);
        }
#pragma unroll
        for (int jd = 0; jd < 8; ++jd) {
            int row = dq * 8 + jd;
            unsigned v32 = (unsigned)f2bf(r0[jd]) | ((unsigned)f2bf(r1[jd]) << 16);
            *(unsigned*)((char*)lt + row * 128 + ((np_ * 4) ^ ((row & 7) << 4))) = v32;
        }
        // ---- compute: per kk, B-frag from private LDS, A-frags direct global
#pragma unroll
        for (int kk = 0; kk < 2; ++kk) {
            const int nb_ = n0 + kk * 32 + lg * 8;
            bf16x8 bfr = *(const bf16x8*)((const char*)lt + lr * 128 +
                                          ((kk * 64 + lg * 16) ^ ((lr & 7) << 4)));
#pragma unroll
            for (int kf = 0; kf < 4; ++kf) {
                bf16x8 afr = *(const bf16x8*)(ab + (size_t)(kf * 16 + lr) * NP + nb_);
                acc[kf] = __builtin_amdgcn_mfma_f32_16x16x32_bf16(afr, bfr, acc[kf], 0, 0, 0);
            }
        }
    }

    // epilogue: lane: d = d0+w*16+lr (N=col), k = kf*16 + lg*4 + r (M=row)
    const int dcol = d0 + w * 16 + lr;
#pragma unroll
    for (int kf = 0; kf < 4; ++kf) {
        int kb = kf * 16 + lg * 4;
        f32x4 c4 = *(const f32x4*)(Cm + (size_t)dcol * NK + kb);
        f32x4 s4 = *(const f32x4*)(a_sum + b * NK + kb);
        f32x4 o = acc[kf] + c4 * s4;
        *(f32x4*)(v + ((size_t)b * ND + dcol) * NK + kb) = o;
    }
}

// ---------------------------------------------------------------------------
// K3: intra-normalize over D per (b,k), then global L2 per b. 1024 threads.
// ---------------------------------------------------------------------------
__global__ __launch_bounds__(1024) void k_norm(
    const float* __restrict__ v, float* __restrict__ out)
{
    __shared__ float ssl[16][64];
    __shared__ float scl[64];
    const int t = threadIdx.x;
    const int k = t & 63, dg = t >> 6;     // dg 0..15
    const int b = blockIdx.x;
    const float* vb = v + (size_t)b * ND * NK;

    float ss = 0.f;
    for (int d = dg; d < ND; d += 16) {
        float val = vb[d * NK + k];
        ss = fmaf(val, val, ss);
    }
    ssl[dg][k] = ss;
    __syncthreads();
    if (t < 64) {
        float tot = 0.f;
#pragma unroll
        for (int i = 0; i < 16; ++i) tot += ssl[i][t];
        float c = tot / (tot + EPS_F);
        float g = c;
#pragma unroll
        for (int mask = 1; mask < 64; mask <<= 1)
            g += __shfl_xor(g, mask, 64);
        scl[t] = 1.0f / (sqrtf(tot + EPS_F) * sqrtf(g + EPS_F));
    }
    __syncthreads();
    float* ob = out + (size_t)b * ND * NK;
    for (int d = dg; d < ND; d += 16)
        ob[d * NK + k] = vb[d * NK + k] * scl[k];
}

// ---------------------------------------------------------------------------
extern "C" void kernel_launch(void* const* d_in, const int* in_sizes, int n_in,
                              void* d_out, int out_size, void* d_ws, size_t ws_size,
                              hipStream_t stream)
{
    const float* x    = (const float*)d_in[0];
    const float* Wm   = (const float*)d_in[1];
    const float* bias = (const float*)d_in[2];
    const float* Cm   = (const float*)d_in[3];
    float* out = (float*)d_out;

    char* ws = (char*)d_ws;
    unsigned short* aT = (unsigned short*)ws;                 // 6,422,528 B
    char* p = ws + (size_t)NB * NK * NP * 2;
    float* a_sum = (float*)p;                                 // 16,384 B
    p += (size_t)NB * NK * 4;
    float* v = (float*)p;                                     // 8,388,608 B
    p += (size_t)NB * ND * NK * 4;
    unsigned short* Wt = (unsigned short*)p;                  // 65,536 B

    hipLaunchKernelGGL(k_wt, dim3(128), dim3(256), 0, stream, Wm, Wt, a_sum);
    dim3 g1((NP + 63) / 64, NB);
    hipLaunchKernelGGL(k_assign, g1, dim3(256), 0, stream, x, Wt, bias, aT, a_sum);
    dim3 g2(ND / 64, NB);
    hipLaunchKernelGGL(k_vlad, g2, dim3(256), 0, stream, x, aT, Cm, a_sum, v);
    hipLaunchKernelGGL(k_norm, dim3(NB), dim3(1024), 0, stream, v, out);
}

// Round 4
// 79.173 us; speedup vs baseline: 2.2370x; 1.3593x over previous
//
#include <hip/hip_runtime.h>
#include <math.h>

#define NB 64
#define NP 784      // 28*28
#define ND 512
#define NK 64
#define EPS_F 1e-12f

typedef float f32x4 __attribute__((ext_vector_type(4)));
typedef short bf16x8 __attribute__((ext_vector_type(8)));

__device__ __forceinline__ unsigned short f2bf(float f) {
    unsigned u = __builtin_bit_cast(unsigned, f);
    u += 0x7fffu + ((u >> 16) & 1u);
    return (unsigned short)(u >> 16);
}

// packed f32x2 -> bf16x2 (RNE), single HW instruction
__device__ __forceinline__ unsigned cvt_pk_bf16(float lo, float hi) {
    unsigned r;
    asm("v_cvt_pk_bf16_f32 %0, %1, %2" : "=v"(r) : "v"(lo), "v"(hi));
    return r;
}

__device__ __forceinline__ bf16x8 pack8(const float* s) {
    union { unsigned u[4]; bf16x8 v; } r;
#pragma unroll
    for (int i = 0; i < 4; ++i) r.u[i] = cvt_pk_bf16(s[2 * i], s[2 * i + 1]);
    return r.v;
}

// async 16B global->LDS (dest must be wave-uniform; HW adds lane*16)
__device__ __forceinline__ void gload16(const void* g, void* l) {
    __builtin_amdgcn_global_load_lds(
        (const __attribute__((address_space(1))) unsigned*)g,
        (__attribute__((address_space(3))) unsigned*)l, 16, 0, 0);
}

// ---------------------------------------------------------------------------
// K0: Wt[k][d] bf16 = W[d][k] fp32; zero a_sum; zero zpad.
// ---------------------------------------------------------------------------
__global__ __launch_bounds__(256) void k_wt(const float* __restrict__ W,
                                            unsigned short* __restrict__ Wt,
                                            float* __restrict__ a_sum,
                                            float* __restrict__ zpad)
{
    int idx = blockIdx.x * 256 + threadIdx.x;   // 0..32767
    int k = idx >> 9, d = idx & 511;
    Wt[idx] = f2bf(W[(size_t)d * NK + k]);
    if (idx < NB * NK) a_sum[idx] = 0.f;
    if (idx < 64) zpad[idx] = 0.f;
}

// ---------------------------------------------------------------------------
// K1: s = x.W + bias ; a = softmax_k(s) ; aT[b][k][n] bf16 ; a_sum[b][k]
// grid (13, 64), 256 threads (4 waves). Tile 64n x 64k, BK=64, 8 steps.
// 2-phase dbuf: x fp32 tile (16KB) + Wt bf16 tile (8KB), both via
// global_load_lds with source-pre-swizzled 16B chunks (chunk ^= row&7).
// LDS 48.25KB -> 3 blocks/CU.
// ---------------------------------------------------------------------------
__global__ __launch_bounds__(256) void k_assign(
    const float* __restrict__ x, const unsigned short* __restrict__ Wt,
    const float* __restrict__ bias, unsigned short* __restrict__ aT,
    float* __restrict__ a_sum)
{
    // [0,16384) xbuf0 | [16384,32768) xbuf1 | [32768,40960) wbuf0 | [40960,49152) wbuf1
    __shared__ __align__(16) char lds[49152];
    __shared__ float asum_l[64];

    const int t = threadIdx.x;
    const int w = t >> 6, l = t & 63, lr = l & 15, lg = l >> 4;
    const int b = blockIdx.y, n0 = blockIdx.x * 64;
    if (t < 64) asum_l[t] = 0.f;

    const float* xb = x + (size_t)b * NP * ND;

    auto STAGE = [&](int d0, int buf) {
        char* xdst = lds + buf * 16384 + w * 1024;
        char* wdst = lds + 32768 + buf * 8192 + w * 1024;
#pragma unroll
        for (int i = 0; i < 4; ++i) {            // x tile: [64n][16 chunks]
            int flat = t + i * 256;
            int n = flat >> 4, c = flat & 15;
            int cs = c ^ (n & 7);
            int ng = n0 + n; if (ng >= NP) ng = NP - 1;   // rows discarded later
            gload16(xb + (size_t)ng * ND + d0 + cs * 4, xdst + i * 4096);
        }
#pragma unroll
        for (int i = 0; i < 2; ++i) {            // Wt tile: [64k][8 chunks]
            int flat = t + i * 256;
            int k = flat >> 3, c = flat & 7;
            int cs = c ^ (k & 7);
            gload16(Wt + (size_t)k * ND + d0 + cs * 8, wdst + i * 4096);
        }
    };

    f32x4 acc[4] = {};
    STAGE(0, 0);
#pragma unroll
    for (int s = 0; s < 8; ++s) {
        __syncthreads();                          // drains vmcnt: buf[s&1] ready
        if (s < 7) STAGE((s + 1) * 64, (s + 1) & 1);
        const char* xT = lds + (s & 1) * 16384;
        const char* wT = lds + 32768 + (s & 1) * 8192;
        const int nr = w * 16 + lr;
#pragma unroll
        for (int kk = 0; kk < 2; ++kk) {
            int cc = kk * 8 + lg * 2;
            float av[8];
            *(f32x4*)&av[0] = *(const f32x4*)(xT + nr * 256 + ((cc ^ (lr & 7)) * 16));
            *(f32x4*)&av[4] = *(const f32x4*)(xT + nr * 256 + (((cc + 1) ^ (lr & 7)) * 16));
            bf16x8 af = pack8(av);
#pragma unroll
            for (int kf = 0; kf < 4; ++kf) {
                int kr = kf * 16 + lr;
                bf16x8 bfr = *(const bf16x8*)(wT + kr * 128 + (((kk * 4 + lg) ^ (kr & 7)) * 16));
                acc[kf] = __builtin_amdgcn_mfma_f32_16x16x32_bf16(af, bfr, acc[kf], 0, 0, 0);
            }
        }
    }

    // softmax over k: lane holds k = kf*16+lr, n = n0 + w*16 + lg*4 + r
    float pv[4][4];
    float part[4] = {0.f, 0.f, 0.f, 0.f};
    float bv[4];
#pragma unroll
    for (int kf = 0; kf < 4; ++kf) bv[kf] = bias[kf * 16 + lr];

#pragma unroll
    for (int r = 0; r < 4; ++r) {
        int n = n0 + w * 16 + lg * 4 + r;
        float sv[4];
        float m = -1e30f;
#pragma unroll
        for (int kf = 0; kf < 4; ++kf) { sv[kf] = acc[kf][r] + bv[kf]; m = fmaxf(m, sv[kf]); }
#pragma unroll
        for (int mask = 1; mask < 16; mask <<= 1)
            m = fmaxf(m, __shfl_xor(m, mask, 64));
        float sum = 0.f;
#pragma unroll
        for (int kf = 0; kf < 4; ++kf) { sv[kf] = __expf(sv[kf] - m); sum += sv[kf]; }
#pragma unroll
        for (int mask = 1; mask < 16; mask <<= 1)
            sum += __shfl_xor(sum, mask, 64);
        float inv = 1.0f / sum;
        bool valid = (n < NP);
#pragma unroll
        for (int kf = 0; kf < 4; ++kf) {
            pv[kf][r] = sv[kf] * inv;
            if (valid) part[kf] += pv[kf][r];
        }
    }
#pragma unroll
    for (int kf = 0; kf < 4; ++kf) atomicAdd(&asum_l[kf * 16 + lr], part[kf]);

    // bounce a -> [k][n] bf16 tile (aliases xbuf0: free after final compute)
    unsigned short* lb = (unsigned short*)lds;
    const int nl0 = w * 16 + lg * 4;
#pragma unroll
    for (int kf = 0; kf < 4; ++kf) {
        int krow = kf * 16 + lr;
#pragma unroll
        for (int rp = 0; rp < 2; ++rp) {
            unsigned v32 = cvt_pk_bf16(pv[kf][2 * rp], pv[kf][2 * rp + 1]);
            *(unsigned*)((char*)lb + krow * 128 +
                         ((nl0 * 2 + rp * 4) ^ ((krow & 7) << 4))) = v32;
        }
    }
    __syncthreads();
    for (int r2 = (t >> 3); r2 < 64; r2 += 32) {
        int n8 = (t & 7) * 8;
        if (n0 + n8 < NP) {
            int4 val = *(const int4*)((const char*)lb + r2 * 128 +
                                      ((n8 * 2) ^ ((r2 & 7) << 4)));
            *(int4*)(aT + ((size_t)b * NK + r2) * NP + n0 + n8) = val;
        }
    }
    if (t < 64) atomicAdd(&a_sum[b * NK + t], asum_l[t]);
}

// ---------------------------------------------------------------------------
// K2: v[b][d][k] = sum_n a[n][k]*x[n][d] + C[d][k]*a_sum[b][k]
// grid (8, 64), 256 threads. A = aT tiles via global_load_lds dbuf (tail
// chunks -> zpad, so a=0 past NP); B = x^T wave-private reg-stage transpose,
// issue-early / write-late (T14). LDS 32KB -> 5 blocks/CU.
// ---------------------------------------------------------------------------
__global__ __launch_bounds__(256) void k_vlad(
    const float* __restrict__ x, const unsigned short* __restrict__ aT,
    const float* __restrict__ Cm, const float* __restrict__ a_sum,
    float* __restrict__ v, const float* __restrict__ zpad)
{
    __shared__ __align__(16) char lds[16384];            // la dbuf 2 x 8KB
    __shared__ __align__(16) unsigned short lxT[8][1024]; // [wave*2+buf][16d x 64n]

    const int t = threadIdx.x;
    const int w = t >> 6, l = t & 63, lr = l & 15, lg = l >> 4;
    const int b = blockIdx.y, d0 = blockIdx.x * 64;
    const int np_ = l & 31, dq = l >> 5;

    const float* xb = x + (size_t)b * NP * ND;
    const unsigned short* ab = aT + (size_t)b * NK * NP;
    const float* xcol = xb + d0 + w * 16 + dq * 8;

    auto STAGE_A = [&](int n0, int buf) {
        char* dst = lds + buf * 8192 + w * 1024;
#pragma unroll
        for (int i = 0; i < 2; ++i) {
            int flat = t + i * 256;
            int k = flat >> 3, c = flat & 7;
            int cs = c ^ (k & 7);
            const void* src = (n0 + cs * 8 + 8 <= NP)
                              ? (const void*)(ab + (size_t)k * NP + n0 + cs * 8)
                              : (const void*)zpad;
            gload16(src, dst + i * 4096);
        }
    };

    float r0[8], r1[8];
    auto LOAD_B = [&](int n0) {
        int nlo = n0 + 2 * np_;
        int na = nlo < NP ? nlo : NP - 1;       // clamped rows multiply a=0
        int nb2 = nlo + 1 < NP ? nlo + 1 : NP - 1;
        *(f32x4*)&r0[0] = *(const f32x4*)(xcol + (size_t)na * ND);
        *(f32x4*)&r0[4] = *(const f32x4*)(xcol + (size_t)na * ND + 4);
        *(f32x4*)&r1[0] = *(const f32x4*)(xcol + (size_t)nb2 * ND);
        *(f32x4*)&r1[4] = *(const f32x4*)(xcol + (size_t)nb2 * ND + 4);
    };
    auto WRITE_B = [&](int buf) {
        unsigned short* lt = lxT[w * 2 + buf];
#pragma unroll
        for (int jd = 0; jd < 8; ++jd) {
            int row = dq * 8 + jd;
            unsigned v32 = cvt_pk_bf16(r0[jd], r1[jd]);
            *(unsigned*)((char*)lt + row * 128 + ((np_ * 4) ^ ((row & 7) << 4))) = v32;
        }
    };

    f32x4 acc[4] = {};
    STAGE_A(0, 0);
    LOAD_B(0);
    WRITE_B(0);
#pragma unroll
    for (int it = 0; it < 13; ++it) {
        __syncthreads();                         // la[it&1] ready, prev readers done
        const int n0 = it * 64;
        if (it < 12) { STAGE_A(n0 + 64, (it + 1) & 1); LOAD_B(n0 + 64); }
        const char* la = lds + (it & 1) * 8192;
        const unsigned short* lt = lxT[w * 2 + (it & 1)];
#pragma unroll
        for (int kk = 0; kk < 2; ++kk) {
            bf16x8 bfr = *(const bf16x8*)((const char*)lt + lr * 128 +
                                          ((kk * 64 + lg * 16) ^ ((lr & 7) << 4)));
#pragma unroll
            for (int kf = 0; kf < 4; ++kf) {
                int kr = kf * 16 + lr;
                bf16x8 afr = *(const bf16x8*)(la + kr * 128 +
                                              (((kk * 4 + lg) ^ (kr & 7)) * 16));
                acc[kf] = __builtin_amdgcn_mfma_f32_16x16x32_bf16(afr, bfr, acc[kf], 0, 0, 0);
            }
        }
        if (it < 12) WRITE_B((it + 1) & 1);      // write-late: loads arrived by now
    }

    // epilogue: d = d0+w*16+lr (col), k = kf*16+lg*4..+3 (rows)
    const int dcol = d0 + w * 16 + lr;
#pragma unroll
    for (int kf = 0; kf < 4; ++kf) {
        int kb = kf * 16 + lg * 4;
        f32x4 c4 = *(const f32x4*)(Cm + (size_t)dcol * NK + kb);
        f32x4 s4 = *(const f32x4*)(a_sum + b * NK + kb);
        f32x4 o = acc[kf] + c4 * s4;
        *(f32x4*)(v + ((size_t)b * ND + dcol) * NK + kb) = o;
    }
}

// ---------------------------------------------------------------------------
// K3: intra-normalize over D per (b,k), then global L2 per b. 1024 threads.
// ---------------------------------------------------------------------------
__global__ __launch_bounds__(1024) void k_norm(
    const float* __restrict__ v, float* __restrict__ out)
{
    __shared__ float ssl[16][64];
    __shared__ float scl[64];
    const int t = threadIdx.x;
    const int k = t & 63, dg = t >> 6;
    const int b = blockIdx.x;
    const float* vb = v + (size_t)b * ND * NK;

    float ss = 0.f;
    for (int d = dg; d < ND; d += 16) {
        float val = vb[d * NK + k];
        ss = fmaf(val, val, ss);
    }
    ssl[dg][k] = ss;
    __syncthreads();
    if (t < 64) {
        float tot = 0.f;
#pragma unroll
        for (int i = 0; i < 16; ++i) tot += ssl[i][t];
        float c = tot / (tot + EPS_F);
        float g = c;
#pragma unroll
        for (int mask = 1; mask < 64; mask <<= 1)
            g += __shfl_xor(g, mask, 64);
        scl[t] = 1.0f / (sqrtf(tot + EPS_F) * sqrtf(g + EPS_F));
    }
    __syncthreads();
    float* ob = out + (size_t)b * ND * NK;
    for (int d = dg; d < ND; d += 16)
        ob[d * NK + k] = vb[d * NK + k] * scl[k];
}

// ---------------------------------------------------------------------------
extern "C" void kernel_launch(void* const* d_in, const int* in_sizes, int n_in,
                              void* d_out, int out_size, void* d_ws, size_t ws_size,
                              hipStream_t stream)
{
    const float* x    = (const float*)d_in[0];
    const float* Wm   = (const float*)d_in[1];
    const float* bias = (const float*)d_in[2];
    const float* Cm   = (const float*)d_in[3];
    float* out = (float*)d_out;

    char* ws = (char*)d_ws;
    unsigned short* aT = (unsigned short*)ws;                 // 6,422,528 B
    char* p = ws + (size_t)NB * NK * NP * 2;
    float* a_sum = (float*)p;                                 // 16,384 B
    p += (size_t)NB * NK * 4;
    float* v = (float*)p;                                     // 8,388,608 B
    p += (size_t)NB * ND * NK * 4;
    unsigned short* Wt = (unsigned short*)p;                  // 65,536 B
    p += (size_t)NK * ND * 2;
    float* zpad = (float*)p;                                  // 256 B

    hipLaunchKernelGGL(k_wt, dim3(128), dim3(256), 0, stream, Wm, Wt, a_sum, zpad);
    dim3 g1((NP + 63) / 64, NB);
    hipLaunchKernelGGL(k_assign, g1, dim3(256), 0, stream, x, Wt, bias, aT, a_sum);
    dim3 g2(ND / 64, NB);
    hipLaunchKernelGGL(k_vlad, g2, dim3(256), 0, stream, x, aT, Cm, a_sum, v, zpad);
    hipLaunchKernelGGL(k_norm, dim3(NB), dim3(1024), 0, stream, v, out);
}

// Round 7
// 74.530 us; speedup vs baseline: 2.3763x; 1.0623x over previous
//
#include <hip/hip_runtime.h>
#include <math.h>

#define NB 64
#define NP 784      // 28*28
#define ND 512
#define NK 64
#define EPS_F 1e-12f

typedef float f32x4 __attribute__((ext_vector_type(4)));
typedef short bf16x8 __attribute__((ext_vector_type(8)));

// Leading barrier: memory-clobber fences pin all LDS/global memory ops.
#define BAR_HEAD() { asm volatile("" ::: "memory"); \
                     __builtin_amdgcn_s_barrier(); \
                     asm volatile("" ::: "memory"); }
// Trailing barrier: rule #18 — "memory" does NOT order register-only MFMA;
// compiler may sink MFMAs + their lgkmcnt waits past s_barrier, leaving
// ds_reads pending when the next iteration's global_load_lds overwrites the
// same buffer. sched_barrier(0) blocks ALL migration; lgkmcnt(0) drains the
// LDS pipe before any wave crosses (nearly free: MFMA reg-deps already
// drained most of it).
#define BAR_TAIL() { __builtin_amdgcn_sched_barrier(0); \
                     asm volatile("s_waitcnt lgkmcnt(0)" ::: "memory"); \
                     __builtin_amdgcn_sched_barrier(0); \
                     __builtin_amdgcn_s_barrier(); \
                     __builtin_amdgcn_sched_barrier(0); }
#define VMCNT6() asm volatile("s_waitcnt vmcnt(6)" ::: "memory")
#define VMCNT0() asm volatile("s_waitcnt vmcnt(0)" ::: "memory")

__device__ __forceinline__ unsigned short f2bf(float f) {
    unsigned u = __builtin_bit_cast(unsigned, f);
    u += 0x7fffu + ((u >> 16) & 1u);
    return (unsigned short)(u >> 16);
}

// packed f32x2 -> bf16x2 (RNE), single HW instruction
__device__ __forceinline__ unsigned cvt_pk_bf16(float lo, float hi) {
    unsigned r;
    asm("v_cvt_pk_bf16_f32 %0, %1, %2" : "=v"(r) : "v"(lo), "v"(hi));
    return r;
}

__device__ __forceinline__ bf16x8 pack8(const float* s) {
    union { unsigned u[4]; bf16x8 v; } r;
#pragma unroll
    for (int i = 0; i < 4; ++i) r.u[i] = cvt_pk_bf16(s[2 * i], s[2 * i + 1]);
    return r.v;
}

// async 16B global->LDS (dest wave-uniform; HW adds lane*16)
__device__ __forceinline__ void gload16(const void* g, void* l) {
    __builtin_amdgcn_global_load_lds(
        (const __attribute__((address_space(1))) unsigned*)g,
        (__attribute__((address_space(3))) unsigned*)l, 16, 0, 0);
}

// ---------------------------------------------------------------------------
// K0: Wt[k][d] bf16 = W[d][k] fp32; zero a_sum; zero zpad.
// ---------------------------------------------------------------------------
__global__ __launch_bounds__(256) void k_wt(const float* __restrict__ W,
                                            unsigned short* __restrict__ Wt,
                                            float* __restrict__ a_sum,
                                            float* __restrict__ zpad)
{
    int idx = blockIdx.x * 256 + threadIdx.x;   // 0..32767
    int k = idx >> 9, d = idx & 511;
    Wt[idx] = f2bf(W[(size_t)d * NK + k]);
    if (idx < NB * NK) a_sum[idx] = 0.f;
    if (idx < 64) zpad[idx] = 0.f;
}

// ---------------------------------------------------------------------------
// K1: s = x.W + bias ; a = softmax_k(s) ; aT[b][k][n] bf16 ; a_sum[b][k]
// grid (13, 64), 256 threads (4 waves). Tile 64n x 64k, BK=64, 8 steps.
// Counted-vmcnt dbuf: STAGE(next) -> vmcnt(6) (cur's 6/wave done, next's 6
// stay in flight through compute) -> BAR_HEAD -> compute -> BAR_TAIL.
// ---------------------------------------------------------------------------
__global__ __launch_bounds__(256) void k_assign(
    const float* __restrict__ x, const unsigned short* __restrict__ Wt,
    const float* __restrict__ bias, unsigned short* __restrict__ aT,
    float* __restrict__ a_sum)
{
    // [0,16384) xbuf0 | [16384,32768) xbuf1 | [32768,40960) wbuf0 | [40960,49152) wbuf1
    __shared__ __align__(16) char lds[49152];
    __shared__ float asum_l[64];

    const int t = threadIdx.x;
    const int w = t >> 6, l = t & 63, lr = l & 15, lg = l >> 4;
    const int b = blockIdx.y, n0 = blockIdx.x * 64;
    if (t < 64) asum_l[t] = 0.f;

    const float* xb = x + (size_t)b * NP * ND;

    auto STAGE = [&](int d0, int buf) {
        char* xdst = lds + buf * 16384 + w * 1024;
        char* wdst = lds + 32768 + buf * 8192 + w * 1024;
#pragma unroll
        for (int i = 0; i < 4; ++i) {            // x tile: [64n][16 chunks] fp32
            int flat = t + i * 256;
            int n = flat >> 4, c = flat & 15;
            int cs = c ^ (n & 7);
            int ng = n0 + n; if (ng >= NP) ng = NP - 1;   // dup rows discarded later
            gload16(xb + (size_t)ng * ND + d0 + cs * 4, xdst + i * 4096);
        }
#pragma unroll
        for (int i = 0; i < 2; ++i) {            // Wt tile: [64k][8 chunks] bf16
            int flat = t + i * 256;
            int k = flat >> 3, c = flat & 7;
            int cs = c ^ (k & 7);
            gload16(Wt + (size_t)k * ND + d0 + cs * 8, wdst + i * 4096);
        }
    };

    f32x4 acc[4] = {};
    STAGE(0, 0);
#pragma unroll
    for (int s = 0; s < 8; ++s) {
        if (s < 7) { STAGE((s + 1) * 64, (s + 1) & 1); VMCNT6(); }
        else       { VMCNT0(); }
        BAR_HEAD();                              // buf[s&1] ready for all waves
        const char* xT = lds + (s & 1) * 16384;
        const char* wT = lds + 32768 + (s & 1) * 8192;
        const int nr = w * 16 + lr;
#pragma unroll
        for (int kk = 0; kk < 2; ++kk) {
            int cc = kk * 8 + lg * 2;
            float av[8];
            *(f32x4*)&av[0] = *(const f32x4*)(xT + nr * 256 + ((cc ^ (lr & 7)) * 16));
            *(f32x4*)&av[4] = *(const f32x4*)(xT + nr * 256 + (((cc + 1) ^ (lr & 7)) * 16));
            bf16x8 af = pack8(av);
#pragma unroll
            for (int kf = 0; kf < 4; ++kf) {
                int kr = kf * 16 + lr;
                bf16x8 bfr = *(const bf16x8*)(wT + kr * 128 + (((kk * 4 + lg) ^ (kr & 7)) * 16));
                acc[kf] = __builtin_amdgcn_mfma_f32_16x16x32_bf16(af, bfr, acc[kf], 0, 0, 0);
            }
        }
        BAR_TAIL();                              // drain LDS pipe, then barrier
    }

    // softmax over k: lane holds k = kf*16+lr, n = n0 + w*16 + lg*4 + r
    float pv[4][4];
    float part[4] = {0.f, 0.f, 0.f, 0.f};
    float bv[4];
#pragma unroll
    for (int kf = 0; kf < 4; ++kf) bv[kf] = bias[kf * 16 + lr];

#pragma unroll
    for (int r = 0; r < 4; ++r) {
        int n = n0 + w * 16 + lg * 4 + r;
        float sv[4];
        float m = -1e30f;
#pragma unroll
        for (int kf = 0; kf < 4; ++kf) { sv[kf] = acc[kf][r] + bv[kf]; m = fmaxf(m, sv[kf]); }
#pragma unroll
        for (int mask = 1; mask < 16; mask <<= 1)
            m = fmaxf(m, __shfl_xor(m, mask, 64));
        float sum = 0.f;
#pragma unroll
        for (int kf = 0; kf < 4; ++kf) { sv[kf] = __expf(sv[kf] - m); sum += sv[kf]; }
#pragma unroll
        for (int mask = 1; mask < 16; mask <<= 1)
            sum += __shfl_xor(sum, mask, 64);
        float inv = 1.0f / sum;
        bool valid = (n < NP);
#pragma unroll
        for (int kf = 0; kf < 4; ++kf) {
            pv[kf][r] = sv[kf] * inv;
            if (valid) part[kf] += pv[kf][r];
        }
    }
#pragma unroll
    for (int kf = 0; kf < 4; ++kf) atomicAdd(&asum_l[kf * 16 + lr], part[kf]);

    // bounce a -> [k][n] bf16 tile (aliases xbuf0: free after final compute)
    unsigned short* lb = (unsigned short*)lds;
    const int nl0 = w * 16 + lg * 4;
#pragma unroll
    for (int kf = 0; kf < 4; ++kf) {
        int krow = kf * 16 + lr;
#pragma unroll
        for (int rp = 0; rp < 2; ++rp) {
            unsigned v32 = cvt_pk_bf16(pv[kf][2 * rp], pv[kf][2 * rp + 1]);
            *(unsigned*)((char*)lb + krow * 128 +
                         ((nl0 * 2 + rp * 4) ^ ((krow & 7) << 4))) = v32;
        }
    }
    __syncthreads();
    for (int r2 = (t >> 3); r2 < 64; r2 += 32) {
        int n8 = (t & 7) * 8;
        if (n0 + n8 < NP) {
            int4 val = *(const int4*)((const char*)lb + r2 * 128 +
                                      ((n8 * 2) ^ ((r2 & 7) << 4)));
            *(int4*)(aT + ((size_t)b * NK + r2) * NP + n0 + n8) = val;
        }
    }
    if (t < 64) atomicAdd(&a_sum[b * NK + t], asum_l[t]);
}

// ---------------------------------------------------------------------------
// K2: v[b][d][k] = sum_n a[n][k]*x[n][d] + C[d][k]*a_sum[b][k]
// grid flat 512, XCD-swizzled so the 8 d-blocks of a batch share one XCD's
// L2 for aT_b. A = aT via gload_lds dbuf (counted vmcnt); B = x^T reg-stage
// transpose, issue-early/write-late (T14). LDS 32KB.
// ---------------------------------------------------------------------------
__global__ __launch_bounds__(256) void k_vlad(
    const float* __restrict__ x, const unsigned short* __restrict__ aT,
    const float* __restrict__ Cm, const float* __restrict__ a_sum,
    float* __restrict__ v, const float* __restrict__ zpad)
{
    __shared__ __align__(16) char lds[16384];             // la dbuf 2 x 8KB
    __shared__ __align__(16) unsigned short lxT[8][1024]; // [wave*2+buf][16d x 64n]

    const int t = threadIdx.x;
    const int w = t >> 6, l = t & 63, lr = l & 15, lg = l >> 4;
    // XCD-bijective decode: same-batch d-blocks land on one XCD (f%8 const per b-group)
    const int f = blockIdx.x;
    const int q = f >> 3;
    const int d0 = (q & 7) * 64;
    const int b  = (f & 7) + 8 * (q >> 3);
    const int np_ = l & 31, dq = l >> 5;

    const float* xb = x + (size_t)b * NP * ND;
    const unsigned short* ab = aT + (size_t)b * NK * NP;
    const float* xcol = xb + d0 + w * 16 + dq * 8;

    auto STAGE_A = [&](int n0, int buf) {
        char* dst = lds + buf * 8192 + w * 1024;
#pragma unroll
        for (int i = 0; i < 2; ++i) {
            int flat = t + i * 256;
            int k = flat >> 3, c = flat & 7;
            int cs = c ^ (k & 7);
            const void* src = (n0 + cs * 8 + 8 <= NP)
                              ? (const void*)(ab + (size_t)k * NP + n0 + cs * 8)
                              : (const void*)zpad;
            gload16(src, dst + i * 4096);
        }
    };

    float r0[8], r1[8];
    auto LOAD_B = [&](int n0) {
        int nlo = n0 + 2 * np_;
        int na = nlo < NP ? nlo : NP - 1;       // clamped rows multiply a=0
        int nb2 = nlo + 1 < NP ? nlo + 1 : NP - 1;
        *(f32x4*)&r0[0] = *(const f32x4*)(xcol + (size_t)na * ND);
        *(f32x4*)&r0[4] = *(const f32x4*)(xcol + (size_t)na * ND + 4);
        *(f32x4*)&r1[0] = *(const f32x4*)(xcol + (size_t)nb2 * ND);
        *(f32x4*)&r1[4] = *(const f32x4*)(xcol + (size_t)nb2 * ND + 4);
    };
    auto WRITE_B = [&](int buf) {
        unsigned short* lt = lxT[w * 2 + buf];
#pragma unroll
        for (int jd = 0; jd < 8; ++jd) {
            int row = dq * 8 + jd;
            unsigned v32 = cvt_pk_bf16(r0[jd], r1[jd]);
            *(unsigned*)((char*)lt + row * 128 + ((np_ * 4) ^ ((row & 7) << 4))) = v32;
        }
    };

    f32x4 acc[4] = {};
    LOAD_B(0);
    STAGE_A(0, 0);
    WRITE_B(0);                                  // auto-waits r0/r1
#pragma unroll
    for (int it = 0; it < 13; ++it) {
        const int n0 = it * 64;
        if (it < 12) { LOAD_B(n0 + 64); STAGE_A(n0 + 64, (it + 1) & 1); VMCNT6(); }
        else         { VMCNT0(); }
        BAR_HEAD();                              // la[it&1] ready
        const char* la = lds + (it & 1) * 8192;
        const unsigned short* lt = lxT[w * 2 + (it & 1)];
#pragma unroll
        for (int kk = 0; kk < 2; ++kk) {
            bf16x8 bfr = *(const bf16x8*)((const char*)lt + lr * 128 +
                                          ((kk * 64 + lg * 16) ^ ((lr & 7) << 4)));
#pragma unroll
            for (int kf = 0; kf < 4; ++kf) {
                int kr = kf * 16 + lr;
                bf16x8 afr = *(const bf16x8*)(la + kr * 128 +
                                              (((kk * 4 + lg) ^ (kr & 7)) * 16));
                acc[kf] = __builtin_amdgcn_mfma_f32_16x16x32_bf16(afr, bfr, acc[kf], 0, 0, 0);
            }
        }
        if (it < 12) WRITE_B((it + 1) & 1);      // write-late: loads arrived under MFMA
        BAR_TAIL();                              // drain LDS pipe, then barrier
    }

    // epilogue: d = d0+w*16+lr (col), k = kf*16+lg*4..+3 (rows)
    const int dcol = d0 + w * 16 + lr;
#pragma unroll
    for (int kf = 0; kf < 4; ++kf) {
        int kb = kf * 16 + lg * 4;
        f32x4 c4 = *(const f32x4*)(Cm + (size_t)dcol * NK + kb);
        f32x4 s4 = *(const f32x4*)(a_sum + b * NK + kb);
        f32x4 o = acc[kf] + c4 * s4;
        *(f32x4*)(v + ((size_t)b * ND + dcol) * NK + kb) = o;
    }
}

// ---------------------------------------------------------------------------
// K3: intra-normalize over D per (b,k), then global L2 per b. 1024 threads.
// ---------------------------------------------------------------------------
__global__ __launch_bounds__(1024) void k_norm(
    const float* __restrict__ v, float* __restrict__ out)
{
    __shared__ float ssl[16][64];
    __shared__ float scl[64];
    const int t = threadIdx.x;
    const int k = t & 63, dg = t >> 6;
    const int b = blockIdx.x;
    const float* vb = v + (size_t)b * ND * NK;

    float ss = 0.f;
    for (int d = dg; d < ND; d += 16) {
        float val = vb[d * NK + k];
        ss = fmaf(val, val, ss);
    }
    ssl[dg][k] = ss;
    __syncthreads();
    if (t < 64) {
        float tot = 0.f;
#pragma unroll
        for (int i = 0; i < 16; ++i) tot += ssl[i][t];
        float c = tot / (tot + EPS_F);
        float g = c;
#pragma unroll
        for (int mask = 1; mask < 64; mask <<= 1)
            g += __shfl_xor(g, mask, 64);
        scl[t] = 1.0f / (sqrtf(tot + EPS_F) * sqrtf(g + EPS_F));
    }
    __syncthreads();
    float* ob = out + (size_t)b * ND * NK;
    for (int d = dg; d < ND; d += 16)
        ob[d * NK + k] = vb[d * NK + k] * scl[k];
}

// ---------------------------------------------------------------------------
extern "C" void kernel_launch(void* const* d_in, const int* in_sizes, int n_in,
                              void* d_out, int out_size, void* d_ws, size_t ws_size,
                              hipStream_t stream)
{
    const float* x    = (const float*)d_in[0];
    const float* Wm   = (const float*)d_in[1];
    const float* bias = (const float*)d_in[2];
    const float* Cm   = (const float*)d_in[3];
    float* out = (float*)d_out;

    char* ws = (char*)d_ws;
    unsigned short* aT = (unsigned short*)ws;                 // 6,422,528 B
    char* p = ws + (size_t)NB * NK * NP * 2;
    float* a_sum = (float*)p;                                 // 16,384 B
    p += (size_t)NB * NK * 4;
    float* v = (float*)p;                                     // 8,388,608 B
    p += (size_t)NB * ND * NK * 4;
    unsigned short* Wt = (unsigned short*)p;                  // 65,536 B
    p += (size_t)NK * ND * 2;
    float* zpad = (float*)p;                                  // 256 B

    hipLaunchKernelGGL(k_wt, dim3(128), dim3(256), 0, stream, Wm, Wt, a_sum, zpad);
    dim3 g1((NP + 63) / 64, NB);
    hipLaunchKernelGGL(k_assign, g1, dim3(256), 0, stream, x, Wt, bias, aT, a_sum);
    hipLaunchKernelGGL(k_vlad, dim3(512), dim3(256), 0, stream, x, aT, Cm, a_sum, v, zpad);
    hipLaunchKernelGGL(k_norm, dim3(NB), dim3(1024), 0, stream, v, out);
}

// Round 8
// 64.588 us; speedup vs baseline: 2.7421x; 1.1539x over previous
//
#include <hip/hip_runtime.h>
#include <math.h>

#define NB 64
#define NP 784      // 28*28
#define ND 512
#define NK 64
#define EPS_F 1e-12f

typedef float f32x4 __attribute__((ext_vector_type(4)));
typedef short bf16x8 __attribute__((ext_vector_type(8)));

// Leading barrier: memory-clobber fences pin all LDS/global memory ops.
#define BAR_HEAD() { asm volatile("" ::: "memory"); \
                     __builtin_amdgcn_s_barrier(); \
                     asm volatile("" ::: "memory"); }
// Trailing barrier: rule #18 — "memory" does NOT order register-only MFMA;
// sched_barrier(0) blocks ALL migration; lgkmcnt(0) drains the LDS pipe
// before any wave crosses (nearly free: MFMA reg-deps drained most of it).
#define BAR_TAIL() { __builtin_amdgcn_sched_barrier(0); \
                     asm volatile("s_waitcnt lgkmcnt(0)" ::: "memory"); \
                     __builtin_amdgcn_sched_barrier(0); \
                     __builtin_amdgcn_s_barrier(); \
                     __builtin_amdgcn_sched_barrier(0); }
#define VMCNT6() asm volatile("s_waitcnt vmcnt(6)" ::: "memory")
#define VMCNT0() asm volatile("s_waitcnt vmcnt(0)" ::: "memory")

__device__ __forceinline__ unsigned short f2bf(float f) {
    unsigned u = __builtin_bit_cast(unsigned, f);
    u += 0x7fffu + ((u >> 16) & 1u);
    return (unsigned short)(u >> 16);
}

__device__ __forceinline__ unsigned cvt_pk_bf16(float lo, float hi) {
    unsigned r;
    asm("v_cvt_pk_bf16_f32 %0, %1, %2" : "=v"(r) : "v"(lo), "v"(hi));
    return r;
}

__device__ __forceinline__ bf16x8 pack8(const float* s) {
    union { unsigned u[4]; bf16x8 v; } r;
#pragma unroll
    for (int i = 0; i < 4; ++i) r.u[i] = cvt_pk_bf16(s[2 * i], s[2 * i + 1]);
    return r.v;
}

// async 16B global->LDS (dest wave-uniform; HW adds lane*16)
__device__ __forceinline__ void gload16(const void* g, void* l) {
    __builtin_amdgcn_global_load_lds(
        (const __attribute__((address_space(1))) unsigned*)g,
        (__attribute__((address_space(3))) unsigned*)l, 16, 0, 0);
}

// ---------------------------------------------------------------------------
// K0: Wt[k][d] bf16 = W[d][k] fp32; zero zpad.
// ---------------------------------------------------------------------------
__global__ __launch_bounds__(256) void k_wt(const float* __restrict__ W,
                                            unsigned short* __restrict__ Wt,
                                            float* __restrict__ zpad)
{
    int idx = blockIdx.x * 256 + threadIdx.x;   // 0..32767
    int k = idx >> 9, d = idx & 511;
    Wt[idx] = f2bf(W[(size_t)d * NK + k]);
    if (idx < 64) zpad[idx] = 0.f;
}

// ---------------------------------------------------------------------------
// K1: s = x.W + bias ; a = softmax_k(s) ; aT[b][k][n] bf16 ;
// a_sum_p[b][blk][k] (deterministic per-block partial, no atomics).
// grid (13, 64), 256 threads (4 waves). Tile 64n x 64k, BK=64, 8 steps.
// Counted-vmcnt dbuf: STAGE(next) -> vmcnt(6) -> BAR_HEAD -> compute -> BAR_TAIL.
// ---------------------------------------------------------------------------
__global__ __launch_bounds__(256) void k_assign(
    const float* __restrict__ x, const unsigned short* __restrict__ Wt,
    const float* __restrict__ bias, unsigned short* __restrict__ aT,
    float* __restrict__ a_sum_p)
{
    // [0,16384) xbuf0 | [16384,32768) xbuf1 | [32768,40960) wbuf0 | [40960,49152) wbuf1
    __shared__ __align__(16) char lds[49152];
    __shared__ float asw[4][64];

    const int t = threadIdx.x;
    const int w = t >> 6, l = t & 63, lr = l & 15, lg = l >> 4;
    const int b = blockIdx.y, n0 = blockIdx.x * 64;

    const float* xb = x + (size_t)b * NP * ND;

    auto STAGE = [&](int d0, int buf) {
        char* xdst = lds + buf * 16384 + w * 1024;
        char* wdst = lds + 32768 + buf * 8192 + w * 1024;
#pragma unroll
        for (int i = 0; i < 4; ++i) {            // x tile: [64n][16 chunks] fp32
            int flat = t + i * 256;
            int n = flat >> 4, c = flat & 15;
            int cs = c ^ (n & 7);
            int ng = n0 + n; if (ng >= NP) ng = NP - 1;   // dup rows discarded later
            gload16(xb + (size_t)ng * ND + d0 + cs * 4, xdst + i * 4096);
        }
#pragma unroll
        for (int i = 0; i < 2; ++i) {            // Wt tile: [64k][8 chunks] bf16
            int flat = t + i * 256;
            int k = flat >> 3, c = flat & 7;
            int cs = c ^ (k & 7);
            gload16(Wt + (size_t)k * ND + d0 + cs * 8, wdst + i * 4096);
        }
    };

    f32x4 acc[4] = {};
    STAGE(0, 0);
#pragma unroll
    for (int s = 0; s < 8; ++s) {
        if (s < 7) { STAGE((s + 1) * 64, (s + 1) & 1); VMCNT6(); }
        else       { VMCNT0(); }
        BAR_HEAD();                              // buf[s&1] ready for all waves
        const char* xT = lds + (s & 1) * 16384;
        const char* wT = lds + 32768 + (s & 1) * 8192;
        const int nr = w * 16 + lr;
#pragma unroll
        for (int kk = 0; kk < 2; ++kk) {
            int cc = kk * 8 + lg * 2;
            float av[8];
            *(f32x4*)&av[0] = *(const f32x4*)(xT + nr * 256 + ((cc ^ (lr & 7)) * 16));
            *(f32x4*)&av[4] = *(const f32x4*)(xT + nr * 256 + (((cc + 1) ^ (lr & 7)) * 16));
            bf16x8 af = pack8(av);
#pragma unroll
            for (int kf = 0; kf < 4; ++kf) {
                int kr = kf * 16 + lr;
                bf16x8 bfr = *(const bf16x8*)(wT + kr * 128 + (((kk * 4 + lg) ^ (kr & 7)) * 16));
                acc[kf] = __builtin_amdgcn_mfma_f32_16x16x32_bf16(af, bfr, acc[kf], 0, 0, 0);
            }
        }
        BAR_TAIL();                              // drain LDS pipe, then barrier
    }

    // softmax over k: lane holds k = kf*16+lr, n = n0 + w*16 + lg*4 + r
    float pv[4][4];
    float part[4] = {0.f, 0.f, 0.f, 0.f};
    float bv[4];
#pragma unroll
    for (int kf = 0; kf < 4; ++kf) bv[kf] = bias[kf * 16 + lr];

#pragma unroll
    for (int r = 0; r < 4; ++r) {
        int n = n0 + w * 16 + lg * 4 + r;
        float sv[4];
        float m = -1e30f;
#pragma unroll
        for (int kf = 0; kf < 4; ++kf) { sv[kf] = acc[kf][r] + bv[kf]; m = fmaxf(m, sv[kf]); }
#pragma unroll
        for (int mask = 1; mask < 16; mask <<= 1)
            m = fmaxf(m, __shfl_xor(m, mask, 64));
        float sum = 0.f;
#pragma unroll
        for (int kf = 0; kf < 4; ++kf) { sv[kf] = __expf(sv[kf] - m); sum += sv[kf]; }
#pragma unroll
        for (int mask = 1; mask < 16; mask <<= 1)
            sum += __shfl_xor(sum, mask, 64);
        float inv = 1.0f / sum;
        bool valid = (n < NP);
#pragma unroll
        for (int kf = 0; kf < 4; ++kf) {
            pv[kf][r] = sv[kf] * inv;
            if (valid) part[kf] += pv[kf][r];
        }
    }
    // deterministic a_sum partial: reduce over lg (lane bits 4,5), per-wave slot
#pragma unroll
    for (int kf = 0; kf < 4; ++kf) {
        part[kf] += __shfl_xor(part[kf], 16, 64);
        part[kf] += __shfl_xor(part[kf], 32, 64);
    }
    if (lg == 0) {
#pragma unroll
        for (int kf = 0; kf < 4; ++kf) asw[w][kf * 16 + lr] = part[kf];
    }

    // bounce a -> [k][n] bf16 tile (aliases xbuf0: free after final compute)
    unsigned short* lb = (unsigned short*)lds;
    const int nl0 = w * 16 + lg * 4;
#pragma unroll
    for (int kf = 0; kf < 4; ++kf) {
        int krow = kf * 16 + lr;
#pragma unroll
        for (int rp = 0; rp < 2; ++rp) {
            unsigned v32 = cvt_pk_bf16(pv[kf][2 * rp], pv[kf][2 * rp + 1]);
            *(unsigned*)((char*)lb + krow * 128 +
                         ((nl0 * 2 + rp * 4) ^ ((krow & 7) << 4))) = v32;
        }
    }
    __syncthreads();
    for (int r2 = (t >> 3); r2 < 64; r2 += 32) {
        int n8 = (t & 7) * 8;
        if (n0 + n8 < NP) {
            int4 val = *(const int4*)((const char*)lb + r2 * 128 +
                                      ((n8 * 2) ^ ((r2 & 7) << 4)));
            *(int4*)(aT + ((size_t)b * NK + r2) * NP + n0 + n8) = val;
        }
    }
    if (t < 64) {
        float s = asw[0][t] + asw[1][t] + asw[2][t] + asw[3][t];  // fixed order
        a_sum_p[((size_t)b * 13 + blockIdx.x) * NK + t] = s;
    }
}

// ---------------------------------------------------------------------------
// K2: v[b][d][k] = sum_n a[n][k]*x[n][d] + C[d][k]*a_sum[b][k]
// Epilogue also emits ssq_p[b][dgrp][k] = sum_{d in tile} v^2 (deterministic
// shfl-reduce), feeding k_scale. a_sum summed from 13 partials (L2-hot).
// grid flat 512, XCD-swizzled. LDS 32KB.
// ---------------------------------------------------------------------------
__global__ __launch_bounds__(256) void k_vlad(
    const float* __restrict__ x, const unsigned short* __restrict__ aT,
    const float* __restrict__ Cm, const float* __restrict__ a_sum_p,
    float* __restrict__ v, const float* __restrict__ zpad,
    float* __restrict__ ssq_p)
{
    __shared__ __align__(16) char lds[16384];             // la dbuf 2 x 8KB
    __shared__ __align__(16) unsigned short lxT[8][1024]; // [wave*2+buf][16d x 64n]
    __shared__ float ssw[4][64];

    const int t = threadIdx.x;
    const int w = t >> 6, l = t & 63, lr = l & 15, lg = l >> 4;
    // XCD-bijective decode: same-batch d-blocks land on one XCD
    const int f = blockIdx.x;
    const int q = f >> 3;
    const int dgrp = q & 7;
    const int d0 = dgrp * 64;
    const int b  = (f & 7) + 8 * (q >> 3);
    const int np_ = l & 31, dq = l >> 5;

    const float* xb = x + (size_t)b * NP * ND;
    const unsigned short* ab = aT + (size_t)b * NK * NP;
    const float* xcol = xb + d0 + w * 16 + dq * 8;

    auto STAGE_A = [&](int n0, int buf) {
        char* dst = lds + buf * 8192 + w * 1024;
#pragma unroll
        for (int i = 0; i < 2; ++i) {
            int flat = t + i * 256;
            int k = flat >> 3, c = flat & 7;
            int cs = c ^ (k & 7);
            const void* src = (n0 + cs * 8 + 8 <= NP)
                              ? (const void*)(ab + (size_t)k * NP + n0 + cs * 8)
                              : (const void*)zpad;
            gload16(src, dst + i * 4096);
        }
    };

    float r0[8], r1[8];
    auto LOAD_B = [&](int n0) {
        int nlo = n0 + 2 * np_;
        int na = nlo < NP ? nlo : NP - 1;       // clamped rows multiply a=0
        int nb2 = nlo + 1 < NP ? nlo + 1 : NP - 1;
        *(f32x4*)&r0[0] = *(const f32x4*)(xcol + (size_t)na * ND);
        *(f32x4*)&r0[4] = *(const f32x4*)(xcol + (size_t)na * ND + 4);
        *(f32x4*)&r1[0] = *(const f32x4*)(xcol + (size_t)nb2 * ND);
        *(f32x4*)&r1[4] = *(const f32x4*)(xcol + (size_t)nb2 * ND + 4);
    };
    auto WRITE_B = [&](int buf) {
        unsigned short* lt = lxT[w * 2 + buf];
#pragma unroll
        for (int jd = 0; jd < 8; ++jd) {
            int row = dq * 8 + jd;
            unsigned v32 = cvt_pk_bf16(r0[jd], r1[jd]);
            *(unsigned*)((char*)lt + row * 128 + ((np_ * 4) ^ ((row & 7) << 4))) = v32;
        }
    };

    f32x4 acc[4] = {};
    LOAD_B(0);
    STAGE_A(0, 0);
    WRITE_B(0);                                  // auto-waits r0/r1
#pragma unroll
    for (int it = 0; it < 13; ++it) {
        const int n0 = it * 64;
        if (it < 12) { LOAD_B(n0 + 64); STAGE_A(n0 + 64, (it + 1) & 1); VMCNT6(); }
        else         { VMCNT0(); }
        BAR_HEAD();                              // la[it&1] ready
        const char* la = lds + (it & 1) * 8192;
        const unsigned short* lt = lxT[w * 2 + (it & 1)];
#pragma unroll
        for (int kk = 0; kk < 2; ++kk) {
            bf16x8 bfr = *(const bf16x8*)((const char*)lt + lr * 128 +
                                          ((kk * 64 + lg * 16) ^ ((lr & 7) << 4)));
#pragma unroll
            for (int kf = 0; kf < 4; ++kf) {
                int kr = kf * 16 + lr;
                bf16x8 afr = *(const bf16x8*)(la + kr * 128 +
                                              (((kk * 4 + lg) ^ (kr & 7)) * 16));
                acc[kf] = __builtin_amdgcn_mfma_f32_16x16x32_bf16(afr, bfr, acc[kf], 0, 0, 0);
            }
        }
        if (it < 12) WRITE_B((it + 1) & 1);      // write-late: loads arrived under MFMA
        BAR_TAIL();                              // drain LDS pipe, then barrier
    }

    // epilogue: d = d0+w*16+lr (col), k = kf*16+lg*4..+3 (rows)
    const int dcol = d0 + w * 16 + lr;
#pragma unroll
    for (int kf = 0; kf < 4; ++kf) {
        int kb = kf * 16 + lg * 4;
        f32x4 s4 = {};
#pragma unroll
        for (int c = 0; c < 13; ++c)            // fixed-order a_sum (L2-hot)
            s4 += *(const f32x4*)(a_sum_p + ((size_t)b * 13 + c) * NK + kb);
        f32x4 c4 = *(const f32x4*)(Cm + (size_t)dcol * NK + kb);
        f32x4 o = acc[kf] + c4 * s4;
        *(f32x4*)(v + ((size_t)b * ND + dcol) * NK + kb) = o;
        // ssq partial over this wave's 16 d (lr lanes): bits 0-3
        f32x4 qq = o * o;
#pragma unroll
        for (int m = 1; m < 16; m <<= 1) {
            qq[0] += __shfl_xor(qq[0], m, 64);
            qq[1] += __shfl_xor(qq[1], m, 64);
            qq[2] += __shfl_xor(qq[2], m, 64);
            qq[3] += __shfl_xor(qq[3], m, 64);
        }
        if (lr == 0) {
            ssw[w][kb + 0] = qq[0]; ssw[w][kb + 1] = qq[1];
            ssw[w][kb + 2] = qq[2]; ssw[w][kb + 3] = qq[3];
        }
    }
    __syncthreads();
    if (t < 64) {
        float s = ssw[0][t] + ssw[1][t] + ssw[2][t] + ssw[3][t];  // fixed order
        ssq_p[((size_t)b * 8 + dgrp) * NK + t] = s;
    }
}

// ---------------------------------------------------------------------------
// K3: scale-only normalize. grid 512 = (b, 64-d group), 256 threads.
// tot[k] = fixed-order sum of 8 ssq partials; scl = 1/(sqrt(tot+e)*sqrt(g+e)).
// ---------------------------------------------------------------------------
__global__ __launch_bounds__(256) void k_scale(
    const float* __restrict__ v, const float* __restrict__ ssq_p,
    float* __restrict__ out)
{
    __shared__ float scl[64];
    const int t = threadIdx.x;
    const int f = blockIdx.x;
    const int b = f >> 3, dg = f & 7;

    if (t < 64) {
        float tot = 0.f;
#pragma unroll
        for (int c = 0; c < 8; ++c) tot += ssq_p[((size_t)b * 8 + c) * NK + t];
        float cc = tot / (tot + EPS_F);
        float g = cc;
#pragma unroll
        for (int mask = 1; mask < 64; mask <<= 1)
            g += __shfl_xor(g, mask, 64);
        scl[t] = 1.0f / (sqrtf(tot + EPS_F) * sqrtf(g + EPS_F));
    }
    __syncthreads();

    const float* vb = v   + ((size_t)b * ND + dg * 64) * NK;
    float*       ob = out + ((size_t)b * ND + dg * 64) * NK;
    f32x4 sc4 = *(const f32x4*)(&scl[(t & 15) * 4]);   // thread's k-quad fixed
#pragma unroll
    for (int i = 0; i < 4; ++i) {
        int idx = i * 256 + t;                  // float4 index; idx&15 == t&15
        int row = idx >> 4;
        f32x4 val = *(const f32x4*)(vb + row * NK + (t & 15) * 4);
        *(f32x4*)(ob + row * NK + (t & 15) * 4) = val * sc4;
    }
}

// ---------------------------------------------------------------------------
extern "C" void kernel_launch(void* const* d_in, const int* in_sizes, int n_in,
                              void* d_out, int out_size, void* d_ws, size_t ws_size,
                              hipStream_t stream)
{
    const float* x    = (const float*)d_in[0];
    const float* Wm   = (const float*)d_in[1];
    const float* bias = (const float*)d_in[2];
    const float* Cm   = (const float*)d_in[3];
    float* out = (float*)d_out;

    char* ws = (char*)d_ws;
    unsigned short* aT = (unsigned short*)ws;                 // 6,422,528 B
    char* p = ws + (size_t)NB * NK * NP * 2;
    float* a_sum_p = (float*)p;                               // 64*13*64*4 = 212,992 B
    p += (size_t)NB * 13 * NK * 4;
    float* v = (float*)p;                                     // 8,388,608 B
    p += (size_t)NB * ND * NK * 4;
    unsigned short* Wt = (unsigned short*)p;                  // 65,536 B
    p += (size_t)NK * ND * 2;
    float* zpad = (float*)p;                                  // 256 B
    p += 256;
    float* ssq_p = (float*)p;                                 // 64*8*64*4 = 131,072 B

    hipLaunchKernelGGL(k_wt, dim3(128), dim3(256), 0, stream, Wm, Wt, zpad);
    dim3 g1((NP + 63) / 64, NB);
    hipLaunchKernelGGL(k_assign, g1, dim3(256), 0, stream, x, Wt, bias, aT, a_sum_p);
    hipLaunchKernelGGL(k_vlad, dim3(512), dim3(256), 0, stream, x, aT, Cm, a_sum_p, v, zpad, ssq_p);
    hipLaunchKernelGGL(k_scale, dim3(512), dim3(256), 0, stream, v, ssq_p, out);
}

// Round 9
// 62.739 us; speedup vs baseline: 2.8229x; 1.0295x over previous
//
#include <hip/hip_runtime.h>
#include <math.h>

#define NB 64
#define NP 784      // 28*28
#define ND 512
#define NK 64
#define EPS_F 1e-12f

typedef float f32x4 __attribute__((ext_vector_type(4)));
typedef short bf16x8 __attribute__((ext_vector_type(8)));

// Leading barrier: memory-clobber fences pin all LDS/global memory ops.
#define BAR_HEAD() { asm volatile("" ::: "memory"); \
                     __builtin_amdgcn_s_barrier(); \
                     asm volatile("" ::: "memory"); }
// Trailing barrier: rule #18 — "memory" does NOT order register-only MFMA;
// sched_barrier(0) blocks ALL migration; lgkmcnt(0) drains the LDS pipe
// before any wave crosses (nearly free: MFMA reg-deps drained most of it).
#define BAR_TAIL() { __builtin_amdgcn_sched_barrier(0); \
                     asm volatile("s_waitcnt lgkmcnt(0)" ::: "memory"); \
                     __builtin_amdgcn_sched_barrier(0); \
                     __builtin_amdgcn_s_barrier(); \
                     __builtin_amdgcn_sched_barrier(0); }
#define VMCNT3() asm volatile("s_waitcnt vmcnt(3)" ::: "memory")
#define VMCNT6() asm volatile("s_waitcnt vmcnt(6)" ::: "memory")
#define VMCNT0() asm volatile("s_waitcnt vmcnt(0)" ::: "memory")

__device__ __forceinline__ unsigned short f2bf(float f) {
    unsigned u = __builtin_bit_cast(unsigned, f);
    u += 0x7fffu + ((u >> 16) & 1u);
    return (unsigned short)(u >> 16);
}

__device__ __forceinline__ unsigned cvt_pk_bf16(float lo, float hi) {
    unsigned r;
    asm("v_cvt_pk_bf16_f32 %0, %1, %2" : "=v"(r) : "v"(lo), "v"(hi));
    return r;
}

__device__ __forceinline__ bf16x8 pack8(const float* s) {
    union { unsigned u[4]; bf16x8 v; } r;
#pragma unroll
    for (int i = 0; i < 4; ++i) r.u[i] = cvt_pk_bf16(s[2 * i], s[2 * i + 1]);
    return r.v;
}

// async 16B global->LDS (dest wave-uniform; HW adds lane*16)
__device__ __forceinline__ void gload16(const void* g, void* l) {
    __builtin_amdgcn_global_load_lds(
        (const __attribute__((address_space(1))) unsigned*)g,
        (__attribute__((address_space(3))) unsigned*)l, 16, 0, 0);
}

// ---------------------------------------------------------------------------
// K0: Wt[k][d] bf16 = W[d][k] fp32; zero zpad.
// ---------------------------------------------------------------------------
__global__ __launch_bounds__(256) void k_wt(const float* __restrict__ W,
                                            unsigned short* __restrict__ Wt,
                                            float* __restrict__ zpad)
{
    int idx = blockIdx.x * 256 + threadIdx.x;   // 0..32767
    int k = idx >> 9, d = idx & 511;
    Wt[idx] = f2bf(W[(size_t)d * NK + k]);
    if (idx < 64) zpad[idx] = 0.f;
}

// ---------------------------------------------------------------------------
// K1: s = x.W + bias ; a = softmax_k(s) ; aT[b][k][n] bf16 ;
// a_sum_p[b][blk][k] (deterministic per-block partial, no atomics).
// grid (13, 64), 256 threads (4 waves). Tile 64n x 64k, BK=32, 16 steps.
// LDS 24.75KB -> 6 blocks/CU capacity -> all 832 blocks co-resident (no
// straggler tail; 3-4 independent blocks/CU overlap vmcnt stalls).
// ---------------------------------------------------------------------------
__global__ __launch_bounds__(256) void k_assign(
    const float* __restrict__ x, const unsigned short* __restrict__ Wt,
    const float* __restrict__ bias, unsigned short* __restrict__ aT,
    float* __restrict__ a_sum_p)
{
    // [0,8192) xbuf0 | [8192,16384) xbuf1 | [16384,20480) wbuf0 | [20480,24576) wbuf1
    __shared__ __align__(16) char lds[24576];
    __shared__ float asw[4][64];

    const int t = threadIdx.x;
    const int w = t >> 6, l = t & 63, lr = l & 15, lg = l >> 4;
    const int b = blockIdx.y, n0 = blockIdx.x * 64;

    const float* xb = x + (size_t)b * NP * ND;

    auto STAGE = [&](int d0, int buf) {
        char* xdst = lds + buf * 8192 + w * 1024;
        char* wdst = lds + 16384 + buf * 4096 + w * 1024;
#pragma unroll
        for (int i = 0; i < 2; ++i) {            // x tile: [64n][8 chunks] fp32
            int flat = t + i * 256;
            int n = flat >> 3, c = flat & 7;
            int cs = c ^ (n & 7);
            int ng = n0 + n; if (ng >= NP) ng = NP - 1;   // dup rows discarded later
            gload16(xb + (size_t)ng * ND + d0 + cs * 4, xdst + i * 4096);
        }
        {                                         // Wt tile: [64k][4 chunks] bf16
            int k = t >> 2, c = t & 3;
            int cs = c ^ (k & 3);
            gload16(Wt + (size_t)k * ND + d0 + cs * 8, wdst);
        }
    };

    f32x4 acc[4] = {};
    STAGE(0, 0);
#pragma unroll
    for (int s = 0; s < 16; ++s) {
        if (s < 15) { STAGE((s + 1) * 32, (s + 1) & 1); VMCNT3(); }
        else        { VMCNT0(); }
        BAR_HEAD();                              // buf[s&1] ready for all waves
        const char* xT = lds + (s & 1) * 8192;
        const char* wT = lds + 16384 + (s & 1) * 4096;
        const int nr = w * 16 + lr;
        const int cc = lg * 2;
        float av[8];
        *(f32x4*)&av[0] = *(const f32x4*)(xT + nr * 128 + ((cc ^ (nr & 7)) * 16));
        *(f32x4*)&av[4] = *(const f32x4*)(xT + nr * 128 + (((cc + 1) ^ (nr & 7)) * 16));
        bf16x8 af = pack8(av);
#pragma unroll
        for (int kf = 0; kf < 4; ++kf) {
            int kr = kf * 16 + lr;
            bf16x8 bfr = *(const bf16x8*)(wT + kr * 64 + ((lg ^ (kr & 3)) * 16));
            acc[kf] = __builtin_amdgcn_mfma_f32_16x16x32_bf16(af, bfr, acc[kf], 0, 0, 0);
        }
        BAR_TAIL();                              // drain LDS pipe, then barrier
    }

    // softmax over k: lane holds k = kf*16+lr, n = n0 + w*16 + lg*4 + r
    float pv[4][4];
    float part[4] = {0.f, 0.f, 0.f, 0.f};
    float bv[4];
#pragma unroll
    for (int kf = 0; kf < 4; ++kf) bv[kf] = bias[kf * 16 + lr];

#pragma unroll
    for (int r = 0; r < 4; ++r) {
        int n = n0 + w * 16 + lg * 4 + r;
        float sv[4];
        float m = -1e30f;
#pragma unroll
        for (int kf = 0; kf < 4; ++kf) { sv[kf] = acc[kf][r] + bv[kf]; m = fmaxf(m, sv[kf]); }
#pragma unroll
        for (int mask = 1; mask < 16; mask <<= 1)
            m = fmaxf(m, __shfl_xor(m, mask, 64));
        float sum = 0.f;
#pragma unroll
        for (int kf = 0; kf < 4; ++kf) { sv[kf] = __expf(sv[kf] - m); sum += sv[kf]; }
#pragma unroll
        for (int mask = 1; mask < 16; mask <<= 1)
            sum += __shfl_xor(sum, mask, 64);
        float inv = 1.0f / sum;
        bool valid = (n < NP);
#pragma unroll
        for (int kf = 0; kf < 4; ++kf) {
            pv[kf][r] = sv[kf] * inv;
            if (valid) part[kf] += pv[kf][r];
        }
    }
    // deterministic a_sum partial: reduce over lg (lane bits 4,5), per-wave slot
#pragma unroll
    for (int kf = 0; kf < 4; ++kf) {
        part[kf] += __shfl_xor(part[kf], 16, 64);
        part[kf] += __shfl_xor(part[kf], 32, 64);
    }
    if (lg == 0) {
#pragma unroll
        for (int kf = 0; kf < 4; ++kf) asw[w][kf * 16 + lr] = part[kf];
    }

    // bounce a -> [k][n] bf16 tile (aliases xbuf0: free after final compute)
    unsigned short* lb = (unsigned short*)lds;
    const int nl0 = w * 16 + lg * 4;
#pragma unroll
    for (int kf = 0; kf < 4; ++kf) {
        int krow = kf * 16 + lr;
#pragma unroll
        for (int rp = 0; rp < 2; ++rp) {
            unsigned v32 = cvt_pk_bf16(pv[kf][2 * rp], pv[kf][2 * rp + 1]);
            *(unsigned*)((char*)lb + krow * 128 +
                         ((nl0 * 2 + rp * 4) ^ ((krow & 7) << 4))) = v32;
        }
    }
    __syncthreads();
    for (int r2 = (t >> 3); r2 < 64; r2 += 32) {
        int n8 = (t & 7) * 8;
        if (n0 + n8 < NP) {
            int4 val = *(const int4*)((const char*)lb + r2 * 128 +
                                      ((n8 * 2) ^ ((r2 & 7) << 4)));
            *(int4*)(aT + ((size_t)b * NK + r2) * NP + n0 + n8) = val;
        }
    }
    if (t < 64) {
        float s = asw[0][t] + asw[1][t] + asw[2][t] + asw[3][t];  // fixed order
        a_sum_p[((size_t)b * 13 + blockIdx.x) * NK + t] = s;
    }
}

// ---------------------------------------------------------------------------
// K2: v[b][d][k] = sum_n a[n][k]*x[n][d] + C[d][k]*a_sum[b][k]
// Epilogue also emits ssq_p[b][dgrp][k] = sum_{d in tile} v^2 (deterministic
// shfl-reduce), feeding k_scale. a_sum summed from 13 partials (L2-hot).
// grid flat 512, XCD-swizzled. LDS 32KB.
// ---------------------------------------------------------------------------
__global__ __launch_bounds__(256) void k_vlad(
    const float* __restrict__ x, const unsigned short* __restrict__ aT,
    const float* __restrict__ Cm, const float* __restrict__ a_sum_p,
    float* __restrict__ v, const float* __restrict__ zpad,
    float* __restrict__ ssq_p)
{
    __shared__ __align__(16) char lds[16384];             // la dbuf 2 x 8KB
    __shared__ __align__(16) unsigned short lxT[8][1024]; // [wave*2+buf][16d x 64n]
    __shared__ float ssw[4][64];

    const int t = threadIdx.x;
    const int w = t >> 6, l = t & 63, lr = l & 15, lg = l >> 4;
    // XCD-bijective decode: same-batch d-blocks land on one XCD
    const int f = blockIdx.x;
    const int q = f >> 3;
    const int dgrp = q & 7;
    const int d0 = dgrp * 64;
    const int b  = (f & 7) + 8 * (q >> 3);
    const int np_ = l & 31, dq = l >> 5;

    const float* xb = x + (size_t)b * NP * ND;
    const unsigned short* ab = aT + (size_t)b * NK * NP;
    const float* xcol = xb + d0 + w * 16 + dq * 8;

    auto STAGE_A = [&](int n0, int buf) {
        char* dst = lds + buf * 8192 + w * 1024;
#pragma unroll
        for (int i = 0; i < 2; ++i) {
            int flat = t + i * 256;
            int k = flat >> 3, c = flat & 7;
            int cs = c ^ (k & 7);
            const void* src = (n0 + cs * 8 + 8 <= NP)
                              ? (const void*)(ab + (size_t)k * NP + n0 + cs * 8)
                              : (const void*)zpad;
            gload16(src, dst + i * 4096);
        }
    };

    float r0[8], r1[8];
    auto LOAD_B = [&](int n0) {
        int nlo = n0 + 2 * np_;
        int na = nlo < NP ? nlo : NP - 1;       // clamped rows multiply a=0
        int nb2 = nlo + 1 < NP ? nlo + 1 : NP - 1;
        *(f32x4*)&r0[0] = *(const f32x4*)(xcol + (size_t)na * ND);
        *(f32x4*)&r0[4] = *(const f32x4*)(xcol + (size_t)na * ND + 4);
        *(f32x4*)&r1[0] = *(const f32x4*)(xcol + (size_t)nb2 * ND);
        *(f32x4*)&r1[4] = *(const f32x4*)(xcol + (size_t)nb2 * ND + 4);
    };
    auto WRITE_B = [&](int buf) {
        unsigned short* lt = lxT[w * 2 + buf];
#pragma unroll
        for (int jd = 0; jd < 8; ++jd) {
            int row = dq * 8 + jd;
            unsigned v32 = cvt_pk_bf16(r0[jd], r1[jd]);
            *(unsigned*)((char*)lt + row * 128 + ((np_ * 4) ^ ((row & 7) << 4))) = v32;
        }
    };

    f32x4 acc[4] = {};
    LOAD_B(0);
    STAGE_A(0, 0);
    WRITE_B(0);                                  // auto-waits r0/r1
#pragma unroll
    for (int it = 0; it < 13; ++it) {
        const int n0 = it * 64;
        if (it < 12) { LOAD_B(n0 + 64); STAGE_A(n0 + 64, (it + 1) & 1); VMCNT6(); }
        else         { VMCNT0(); }
        BAR_HEAD();                              // la[it&1] ready
        const char* la = lds + (it & 1) * 8192;
        const unsigned short* lt = lxT[w * 2 + (it & 1)];
#pragma unroll
        for (int kk = 0; kk < 2; ++kk) {
            bf16x8 bfr = *(const bf16x8*)((const char*)lt + lr * 128 +
                                          ((kk * 64 + lg * 16) ^ ((lr & 7) << 4)));
#pragma unroll
            for (int kf = 0; kf < 4; ++kf) {
                int kr = kf * 16 + lr;
                bf16x8 afr = *(const bf16x8*)(la + kr * 128 +
                                              (((kk * 4 + lg) ^ (kr & 7)) * 16));
                acc[kf] = __builtin_amdgcn_mfma_f32_16x16x32_bf16(afr, bfr, acc[kf], 0, 0, 0);
            }
        }
        if (it < 12) WRITE_B((it + 1) & 1);      // write-late: loads arrived under MFMA
        BAR_TAIL();                              // drain LDS pipe, then barrier
    }

    // epilogue: d = d0+w*16+lr (col), k = kf*16+lg*4..+3 (rows)
    const int dcol = d0 + w * 16 + lr;
#pragma unroll
    for (int kf = 0; kf < 4; ++kf) {
        int kb = kf * 16 + lg * 4;
        f32x4 s4 = {};
#pragma unroll
        for (int c = 0; c < 13; ++c)            // fixed-order a_sum (L2-hot)
            s4 += *(const f32x4*)(a_sum_p + ((size_t)b * 13 + c) * NK + kb);
        f32x4 c4 = *(const f32x4*)(Cm + (size_t)dcol * NK + kb);
        f32x4 o = acc[kf] + c4 * s4;
        *(f32x4*)(v + ((size_t)b * ND + dcol) * NK + kb) = o;
        // ssq partial over this wave's 16 d (lr lanes): bits 0-3
        f32x4 qq = o * o;
#pragma unroll
        for (int m = 1; m < 16; m <<= 1) {
            qq[0] += __shfl_xor(qq[0], m, 64);
            qq[1] += __shfl_xor(qq[1], m, 64);
            qq[2] += __shfl_xor(qq[2], m, 64);
            qq[3] += __shfl_xor(qq[3], m, 64);
        }
        if (lr == 0) {
            ssw[w][kb + 0] = qq[0]; ssw[w][kb + 1] = qq[1];
            ssw[w][kb + 2] = qq[2]; ssw[w][kb + 3] = qq[3];
        }
    }
    __syncthreads();
    if (t < 64) {
        float s = ssw[0][t] + ssw[1][t] + ssw[2][t] + ssw[3][t];  // fixed order
        ssq_p[((size_t)b * 8 + dgrp) * NK + t] = s;
    }
}

// ---------------------------------------------------------------------------
// K3: scale-only normalize. grid 512 = (b, 64-d group), 256 threads.
// ---------------------------------------------------------------------------
__global__ __launch_bounds__(256) void k_scale(
    const float* __restrict__ v, const float* __restrict__ ssq_p,
    float* __restrict__ out)
{
    __shared__ float scl[64];
    const int t = threadIdx.x;
    const int f = blockIdx.x;
    const int b = f >> 3, dg = f & 7;

    if (t < 64) {
        float tot = 0.f;
#pragma unroll
        for (int c = 0; c < 8; ++c) tot += ssq_p[((size_t)b * 8 + c) * NK + t];
        float cc = tot / (tot + EPS_F);
        float g = cc;
#pragma unroll
        for (int mask = 1; mask < 64; mask <<= 1)
            g += __shfl_xor(g, mask, 64);
        scl[t] = 1.0f / (sqrtf(tot + EPS_F) * sqrtf(g + EPS_F));
    }
    __syncthreads();

    const float* vb = v   + ((size_t)b * ND + dg * 64) * NK;
    float*       ob = out + ((size_t)b * ND + dg * 64) * NK;
    f32x4 sc4 = *(const f32x4*)(&scl[(t & 15) * 4]);   // thread's k-quad fixed
#pragma unroll
    for (int i = 0; i < 4; ++i) {
        int idx = i * 256 + t;                  // float4 index; idx&15 == t&15
        int row = idx >> 4;
        f32x4 val = *(const f32x4*)(vb + row * NK + (t & 15) * 4);
        *(f32x4*)(ob + row * NK + (t & 15) * 4) = val * sc4;
    }
}

// ---------------------------------------------------------------------------
extern "C" void kernel_launch(void* const* d_in, const int* in_sizes, int n_in,
                              void* d_out, int out_size, void* d_ws, size_t ws_size,
                              hipStream_t stream)
{
    const float* x    = (const float*)d_in[0];
    const float* Wm   = (const float*)d_in[1];
    const float* bias = (const float*)d_in[2];
    const float* Cm   = (const float*)d_in[3];
    float* out = (float*)d_out;

    char* ws = (char*)d_ws;
    unsigned short* aT = (unsigned short*)ws;                 // 6,422,528 B
    char* p = ws + (size_t)NB * NK * NP * 2;
    float* a_sum_p = (float*)p;                               // 212,992 B
    p += (size_t)NB * 13 * NK * 4;
    float* v = (float*)p;                                     // 8,388,608 B
    p += (size_t)NB * ND * NK * 4;
    unsigned short* Wt = (unsigned short*)p;                  // 65,536 B
    p += (size_t)NK * ND * 2;
    float* zpad = (float*)p;                                  // 256 B
    p += 256;
    float* ssq_p = (float*)p;                                 // 131,072 B

    hipLaunchKernelGGL(k_wt, dim3(128), dim3(256), 0, stream, Wm, Wt, zpad);
    dim3 g1((NP + 63) / 64, NB);
    hipLaunchKernelGGL(k_assign, g1, dim3(256), 0, stream, x, Wt, bias, aT, a_sum_p);
    hipLaunchKernelGGL(k_vlad, dim3(512), dim3(256), 0, stream, x, aT, Cm, a_sum_p, v, zpad, ssq_p);
    hipLaunchKernelGGL(k_scale, dim3(512), dim3(256), 0, stream, v, ssq_p, out);
}

// Round 10
// 59.808 us; speedup vs baseline: 2.9613x; 1.0490x over previous
//
#include <hip/hip_runtime.h>
#include <math.h>

#define NB 64
#define NP 784      // 28*28
#define ND 512
#define NK 64
#define EPS_F 1e-12f

typedef float f32x4 __attribute__((ext_vector_type(4)));
typedef short bf16x8 __attribute__((ext_vector_type(8)));

// Leading barrier: memory-clobber fences pin all LDS/global memory ops.
#define BAR_HEAD() { asm volatile("" ::: "memory"); \
                     __builtin_amdgcn_s_barrier(); \
                     asm volatile("" ::: "memory"); }
// Trailing barrier: rule #18 — "memory" does NOT order register-only MFMA;
// sched_barrier(0) blocks ALL migration; lgkmcnt(0) drains the LDS pipe
// before any wave crosses.
#define BAR_TAIL() { __builtin_amdgcn_sched_barrier(0); \
                     asm volatile("s_waitcnt lgkmcnt(0)" ::: "memory"); \
                     __builtin_amdgcn_sched_barrier(0); \
                     __builtin_amdgcn_s_barrier(); \
                     __builtin_amdgcn_sched_barrier(0); }
#define VMCNT(n) asm volatile("s_waitcnt vmcnt(" #n ")" ::: "memory")

__device__ __forceinline__ unsigned short f2bf(float f) {
    unsigned u = __builtin_bit_cast(unsigned, f);
    u += 0x7fffu + ((u >> 16) & 1u);
    return (unsigned short)(u >> 16);
}

__device__ __forceinline__ unsigned cvt_pk_bf16(float lo, float hi) {
    unsigned r;
    asm("v_cvt_pk_bf16_f32 %0, %1, %2" : "=v"(r) : "v"(lo), "v"(hi));
    return r;
}

__device__ __forceinline__ bf16x8 pack8(const float* s) {
    union { unsigned u[4]; bf16x8 v; } r;
#pragma unroll
    for (int i = 0; i < 4; ++i) r.u[i] = cvt_pk_bf16(s[2 * i], s[2 * i + 1]);
    return r.v;
}

// async 16B global->LDS (dest wave-uniform; HW adds lane*16)
__device__ __forceinline__ void gload16(const void* g, void* l) {
    __builtin_amdgcn_global_load_lds(
        (const __attribute__((address_space(1))) unsigned*)g,
        (__attribute__((address_space(3))) unsigned*)l, 16, 0, 0);
}

// ---------------------------------------------------------------------------
// K0: Wt[k][d] bf16 = W[d][k] fp32; zero zpad.
// ---------------------------------------------------------------------------
__global__ __launch_bounds__(256) void k_wt(const float* __restrict__ W,
                                            unsigned short* __restrict__ Wt,
                                            float* __restrict__ zpad)
{
    int idx = blockIdx.x * 256 + threadIdx.x;   // 0..32767
    int k = idx >> 9, d = idx & 511;
    Wt[idx] = f2bf(W[(size_t)d * NK + k]);
    if (idx < 64) zpad[idx] = 0.f;
}

// ---------------------------------------------------------------------------
// K1: s = x.W + bias ; a = softmax_k(s) ; aT[b][k][n] bf16 ;
// a_sum_p[b][blk][k] (deterministic partials). grid (13,64), 4 waves.
// Tile 64n x 64k, BK=32, 16 steps, TRIPLE-buffered gload_lds staging:
// tile s+2 issued at iter s -> 2 iterations of HBM-latency cover.
// Queue at iter s: [T(s):3?, T(s+1):3, T(s+2):3] -> vmcnt(6); tail 3/0.
// LDS 36.9KB -> 4 blocks/CU.
// ---------------------------------------------------------------------------
__global__ __launch_bounds__(256) void k_assign(
    const float* __restrict__ x, const unsigned short* __restrict__ Wt,
    const float* __restrict__ bias, unsigned short* __restrict__ aT,
    float* __restrict__ a_sum_p)
{
    // [0,24576) xbuf x3 (8KB each) | [24576,36864) wbuf x3 (4KB each)
    __shared__ __align__(16) char lds[36864];
    __shared__ float asw[4][64];

    const int t = threadIdx.x;
    const int w = t >> 6, l = t & 63, lr = l & 15, lg = l >> 4;
    const int b = blockIdx.y, n0 = blockIdx.x * 64;

    const float* xb = x + (size_t)b * NP * ND;

    auto STAGE = [&](int d0, int buf) {
        char* xdst = lds + buf * 8192 + w * 1024;
        char* wdst = lds + 24576 + buf * 4096 + w * 1024;
#pragma unroll
        for (int i = 0; i < 2; ++i) {            // x tile: [64n][8 chunks] fp32
            int flat = t + i * 256;
            int n = flat >> 3, c = flat & 7;
            int cs = c ^ (n & 7);
            int ng = n0 + n; if (ng >= NP) ng = NP - 1;   // dup rows discarded later
            gload16(xb + (size_t)ng * ND + d0 + cs * 4, xdst + i * 4096);
        }
        {                                         // Wt tile: [64k][4 chunks] bf16
            int k = t >> 2, c = t & 3;
            int cs = c ^ (k & 3);
            gload16(Wt + (size_t)k * ND + d0 + cs * 8, wdst);
        }
    };

    f32x4 acc[4] = {};
    STAGE(0, 0);
    STAGE(32, 1);
#pragma unroll
    for (int s = 0; s < 16; ++s) {
        if (s < 14)      { STAGE((s + 2) * 32, (s + 2) % 3); VMCNT(6); }
        else if (s == 14) { VMCNT(3); }
        else              { VMCNT(0); }
        BAR_HEAD();                              // buf[s%3] ready for all waves
        const char* xT = lds + (s % 3) * 8192;
        const char* wT = lds + 24576 + (s % 3) * 4096;
        const int nr = w * 16 + lr;
        const int cc = lg * 2;
        float av[8];
        *(f32x4*)&av[0] = *(const f32x4*)(xT + nr * 128 + ((cc ^ (nr & 7)) * 16));
        *(f32x4*)&av[4] = *(const f32x4*)(xT + nr * 128 + (((cc + 1) ^ (nr & 7)) * 16));
        bf16x8 af = pack8(av);
#pragma unroll
        for (int kf = 0; kf < 4; ++kf) {
            int kr = kf * 16 + lr;
            bf16x8 bfr = *(const bf16x8*)(wT + kr * 64 + ((lg ^ (kr & 3)) * 16));
            acc[kf] = __builtin_amdgcn_mfma_f32_16x16x32_bf16(af, bfr, acc[kf], 0, 0, 0);
        }
        BAR_TAIL();                              // drain LDS pipe, then barrier
    }

    // softmax over k: lane holds k = kf*16+lr, n = n0 + w*16 + lg*4 + r
    float pv[4][4];
    float part[4] = {0.f, 0.f, 0.f, 0.f};
    float bv[4];
#pragma unroll
    for (int kf = 0; kf < 4; ++kf) bv[kf] = bias[kf * 16 + lr];

#pragma unroll
    for (int r = 0; r < 4; ++r) {
        int n = n0 + w * 16 + lg * 4 + r;
        float sv[4];
        float m = -1e30f;
#pragma unroll
        for (int kf = 0; kf < 4; ++kf) { sv[kf] = acc[kf][r] + bv[kf]; m = fmaxf(m, sv[kf]); }
#pragma unroll
        for (int mask = 1; mask < 16; mask <<= 1)
            m = fmaxf(m, __shfl_xor(m, mask, 64));
        float sum = 0.f;
#pragma unroll
        for (int kf = 0; kf < 4; ++kf) { sv[kf] = __expf(sv[kf] - m); sum += sv[kf]; }
#pragma unroll
        for (int mask = 1; mask < 16; mask <<= 1)
            sum += __shfl_xor(sum, mask, 64);
        float inv = 1.0f / sum;
        bool valid = (n < NP);
#pragma unroll
        for (int kf = 0; kf < 4; ++kf) {
            pv[kf][r] = sv[kf] * inv;
            if (valid) part[kf] += pv[kf][r];
        }
    }
    // deterministic a_sum partial: reduce over lg (lane bits 4,5), per-wave slot
#pragma unroll
    for (int kf = 0; kf < 4; ++kf) {
        part[kf] += __shfl_xor(part[kf], 16, 64);
        part[kf] += __shfl_xor(part[kf], 32, 64);
    }
    if (lg == 0) {
#pragma unroll
        for (int kf = 0; kf < 4; ++kf) asw[w][kf * 16 + lr] = part[kf];
    }

    // bounce a -> [k][n] bf16 tile (aliases xbuf0: free after final compute)
    unsigned short* lb = (unsigned short*)lds;
    const int nl0 = w * 16 + lg * 4;
#pragma unroll
    for (int kf = 0; kf < 4; ++kf) {
        int krow = kf * 16 + lr;
#pragma unroll
        for (int rp = 0; rp < 2; ++rp) {
            unsigned v32 = cvt_pk_bf16(pv[kf][2 * rp], pv[kf][2 * rp + 1]);
            *(unsigned*)((char*)lb + krow * 128 +
                         ((nl0 * 2 + rp * 4) ^ ((krow & 7) << 4))) = v32;
        }
    }
    __syncthreads();
    for (int r2 = (t >> 3); r2 < 64; r2 += 32) {
        int n8 = (t & 7) * 8;
        if (n0 + n8 < NP) {
            int4 val = *(const int4*)((const char*)lb + r2 * 128 +
                                      ((n8 * 2) ^ ((r2 & 7) << 4)));
            *(int4*)(aT + ((size_t)b * NK + r2) * NP + n0 + n8) = val;
        }
    }
    if (t < 64) {
        float s = asw[0][t] + asw[1][t] + asw[2][t] + asw[3][t];  // fixed order
        a_sum_p[((size_t)b * 13 + blockIdx.x) * NK + t] = s;
    }
}

// ---------------------------------------------------------------------------
// K2: v[b][d][k] = sum_n a[n][k]*x[n][d] + C[d][k]*a_sum[b][k]
// Depth-2 register pipeline for x (LOAD_B): tile it+2 loaded at iter it into
// set[it&1]; WRITE_B consumes the set loaded ONE FULL iteration earlier.
// Queue at iter it: [SA(it):2, LB(it+1):4, SA(it+1):2, LB(it+2):4] -> vmcnt(10).
// grid flat 512, XCD-swizzled. Epilogue: ssq partials (deterministic).
// ---------------------------------------------------------------------------
__global__ __launch_bounds__(256) void k_vlad(
    const float* __restrict__ x, const unsigned short* __restrict__ aT,
    const float* __restrict__ Cm, const float* __restrict__ a_sum_p,
    float* __restrict__ v, const float* __restrict__ zpad,
    float* __restrict__ ssq_p)
{
    __shared__ __align__(16) char lds[16384];             // la dbuf 2 x 8KB
    __shared__ __align__(16) unsigned short lxT[8][1024]; // [wave*2+buf][16d x 64n]
    __shared__ float ssw[4][64];

    const int t = threadIdx.x;
    const int w = t >> 6, l = t & 63, lr = l & 15, lg = l >> 4;
    // XCD-bijective decode: same-batch d-blocks land on one XCD
    const int f = blockIdx.x;
    const int q = f >> 3;
    const int dgrp = q & 7;
    const int d0 = dgrp * 64;
    const int b  = (f & 7) + 8 * (q >> 3);
    const int np_ = l & 31, dq = l >> 5;

    const float* xb = x + (size_t)b * NP * ND;
    const unsigned short* ab = aT + (size_t)b * NK * NP;
    const float* xcol = xb + d0 + w * 16 + dq * 8;

    auto STAGE_A = [&](int n0, int buf) {
        char* dst = lds + buf * 8192 + w * 1024;
#pragma unroll
        for (int i = 0; i < 2; ++i) {
            int flat = t + i * 256;
            int k = flat >> 3, c = flat & 7;
            int cs = c ^ (k & 7);
            const void* src = (n0 + cs * 8 + 8 <= NP)
                              ? (const void*)(ab + (size_t)k * NP + n0 + cs * 8)
                              : (const void*)zpad;
            gload16(src, dst + i * 4096);
        }
    };

    float r0[2][8], r1[2][8];                    // two sets; indices compile-time
    auto LOAD_B = [&](int n0, int set) {
        int nlo = n0 + 2 * np_;
        int na = nlo < NP ? nlo : NP - 1;       // clamped rows multiply a=0
        int nb2 = nlo + 1 < NP ? nlo + 1 : NP - 1;
        *(f32x4*)&r0[set][0] = *(const f32x4*)(xcol + (size_t)na * ND);
        *(f32x4*)&r0[set][4] = *(const f32x4*)(xcol + (size_t)na * ND + 4);
        *(f32x4*)&r1[set][0] = *(const f32x4*)(xcol + (size_t)nb2 * ND);
        *(f32x4*)&r1[set][4] = *(const f32x4*)(xcol + (size_t)nb2 * ND + 4);
    };
    auto WRITE_B = [&](int buf, int set) {
        unsigned short* lt = lxT[w * 2 + buf];
#pragma unroll
        for (int jd = 0; jd < 8; ++jd) {
            int row = dq * 8 + jd;
            unsigned v32 = cvt_pk_bf16(r0[set][jd], r1[set][jd]);
            *(unsigned*)((char*)lt + row * 128 + ((np_ * 4) ^ ((row & 7) << 4))) = v32;
        }
    };

    f32x4 acc[4] = {};
    LOAD_B(0, 0);                                // tile 0 -> set0
    STAGE_A(0, 0);
    WRITE_B(0, 0);                               // auto-waits LB(0)
    LOAD_B(64, 1);                               // tile 1 -> set1
#pragma unroll
    for (int it = 0; it < 13; ++it) {
        const int n0 = it * 64;
        if (it <= 10) {
            STAGE_A(n0 + 64, (it + 1) & 1);
            LOAD_B(n0 + 128, it & 1);            // tile it+2 -> set[it&1]
            VMCNT(10);
        } else if (it == 11) {
            STAGE_A(n0 + 64, (it + 1) & 1);
            VMCNT(6);
        } else {
            VMCNT(0);
        }
        BAR_HEAD();                              // la[it&1] ready
        const char* la = lds + (it & 1) * 8192;
        const unsigned short* lt = lxT[w * 2 + (it & 1)];
#pragma unroll
        for (int kk = 0; kk < 2; ++kk) {
            bf16x8 bfr = *(const bf16x8*)((const char*)lt + lr * 128 +
                                          ((kk * 64 + lg * 16) ^ ((lr & 7) << 4)));
#pragma unroll
            for (int kf = 0; kf < 4; ++kf) {
                int kr = kf * 16 + lr;
                bf16x8 afr = *(const bf16x8*)(la + kr * 128 +
                                              (((kk * 4 + lg) ^ (kr & 7)) * 16));
                acc[kf] = __builtin_amdgcn_mfma_f32_16x16x32_bf16(afr, bfr, acc[kf], 0, 0, 0);
            }
        }
        if (it < 12) WRITE_B((it + 1) & 1, (it + 1) & 1);  // tile it+1 (1 iter old)
        BAR_TAIL();                              // drain LDS pipe, then barrier
    }

    // epilogue: d = d0+w*16+lr (col), k = kf*16+lg*4..+3 (rows)
    const int dcol = d0 + w * 16 + lr;
#pragma unroll
    for (int kf = 0; kf < 4; ++kf) {
        int kb = kf * 16 + lg * 4;
        f32x4 s4 = {};
#pragma unroll
        for (int c = 0; c < 13; ++c)            // fixed-order a_sum (L2-hot)
            s4 += *(const f32x4*)(a_sum_p + ((size_t)b * 13 + c) * NK + kb);
        f32x4 c4 = *(const f32x4*)(Cm + (size_t)dcol * NK + kb);
        f32x4 o = acc[kf] + c4 * s4;
        *(f32x4*)(v + ((size_t)b * ND + dcol) * NK + kb) = o;
        // ssq partial over this wave's 16 d (lr lanes): bits 0-3
        f32x4 qq = o * o;
#pragma unroll
        for (int m = 1; m < 16; m <<= 1) {
            qq[0] += __shfl_xor(qq[0], m, 64);
            qq[1] += __shfl_xor(qq[1], m, 64);
            qq[2] += __shfl_xor(qq[2], m, 64);
            qq[3] += __shfl_xor(qq[3], m, 64);
        }
        if (lr == 0) {
            ssw[w][kb + 0] = qq[0]; ssw[w][kb + 1] = qq[1];
            ssw[w][kb + 2] = qq[2]; ssw[w][kb + 3] = qq[3];
        }
    }
    __syncthreads();
    if (t < 64) {
        float s = ssw[0][t] + ssw[1][t] + ssw[2][t] + ssw[3][t];  // fixed order
        ssq_p[((size_t)b * 8 + dgrp) * NK + t] = s;
    }
}

// ---------------------------------------------------------------------------
// K3: scale-only normalize. grid 512 = (b, 64-d group), 256 threads.
// ---------------------------------------------------------------------------
__global__ __launch_bounds__(256) void k_scale(
    const float* __restrict__ v, const float* __restrict__ ssq_p,
    float* __restrict__ out)
{
    __shared__ float scl[64];
    const int t = threadIdx.x;
    const int f = blockIdx.x;
    const int b = f >> 3, dg = f & 7;

    if (t < 64) {
        float tot = 0.f;
#pragma unroll
        for (int c = 0; c < 8; ++c) tot += ssq_p[((size_t)b * 8 + c) * NK + t];
        float cc = tot / (tot + EPS_F);
        float g = cc;
#pragma unroll
        for (int mask = 1; mask < 64; mask <<= 1)
            g += __shfl_xor(g, mask, 64);
        scl[t] = 1.0f / (sqrtf(tot + EPS_F) * sqrtf(g + EPS_F));
    }
    __syncthreads();

    const float* vb = v   + ((size_t)b * ND + dg * 64) * NK;
    float*       ob = out + ((size_t)b * ND + dg * 64) * NK;
    f32x4 sc4 = *(const f32x4*)(&scl[(t & 15) * 4]);   // thread's k-quad fixed
#pragma unroll
    for (int i = 0; i < 4; ++i) {
        int idx = i * 256 + t;                  // float4 index; idx&15 == t&15
        int row = idx >> 4;
        f32x4 val = *(const f32x4*)(vb + row * NK + (t & 15) * 4);
        *(f32x4*)(ob + row * NK + (t & 15) * 4) = val * sc4;
    }
}

// ---------------------------------------------------------------------------
extern "C" void kernel_launch(void* const* d_in, const int* in_sizes, int n_in,
                              void* d_out, int out_size, void* d_ws, size_t ws_size,
                              hipStream_t stream)
{
    const float* x    = (const float*)d_in[0];
    const float* Wm   = (const float*)d_in[1];
    const float* bias = (const float*)d_in[2];
    const float* Cm   = (const float*)d_in[3];
    float* out = (float*)d_out;

    char* ws = (char*)d_ws;
    unsigned short* aT = (unsigned short*)ws;                 // 6,422,528 B
    char* p = ws + (size_t)NB * NK * NP * 2;
    float* a_sum_p = (float*)p;                               // 212,992 B
    p += (size_t)NB * 13 * NK * 4;
    float* v = (float*)p;                                     // 8,388,608 B
    p += (size_t)NB * ND * NK * 4;
    unsigned short* Wt = (unsigned short*)p;                  // 65,536 B
    p += (size_t)NK * ND * 2;
    float* zpad = (float*)p;                                  // 256 B
    p += 256;
    float* ssq_p = (float*)p;                                 // 131,072 B

    hipLaunchKernelGGL(k_wt, dim3(128), dim3(256), 0, stream, Wm, Wt, zpad);
    dim3 g1((NP + 63) / 64, NB);
    hipLaunchKernelGGL(k_assign, g1, dim3(256), 0, stream, x, Wt, bias, aT, a_sum_p);
    hipLaunchKernelGGL(k_vlad, dim3(512), dim3(256), 0, stream, x, aT, Cm, a_sum_p, v, zpad, ssq_p);
    hipLaunchKernelGGL(k_scale, dim3(512), dim3(256), 0, stream, v, ssq_p, out);
}

// Round 11
// 59.118 us; speedup vs baseline: 2.9958x; 1.0117x over previous
//
#include <hip/hip_runtime.h>
#include <math.h>

#define NB 64
#define NP 784      // 28*28
#define ND 512
#define NK 64
#define EPS_F 1e-12f

typedef float f32x4 __attribute__((ext_vector_type(4)));
typedef short bf16x8 __attribute__((ext_vector_type(8)));

// Leading barrier: memory-clobber fences pin all LDS/global memory ops.
#define BAR_HEAD() { asm volatile("" ::: "memory"); \
                     __builtin_amdgcn_s_barrier(); \
                     asm volatile("" ::: "memory"); }
// Trailing barrier: rule #18 — "memory" does NOT order register-only MFMA;
// sched_barrier(0) blocks ALL migration; lgkmcnt(0) drains the LDS pipe
// before any wave crosses.
#define BAR_TAIL() { __builtin_amdgcn_sched_barrier(0); \
                     asm volatile("s_waitcnt lgkmcnt(0)" ::: "memory"); \
                     __builtin_amdgcn_sched_barrier(0); \
                     __builtin_amdgcn_s_barrier(); \
                     __builtin_amdgcn_sched_barrier(0); }
#define VMCNT(n) asm volatile("s_waitcnt vmcnt(" #n ")" ::: "memory")

__device__ __forceinline__ unsigned short f2bf(float f) {
    unsigned u = __builtin_bit_cast(unsigned, f);
    u += 0x7fffu + ((u >> 16) & 1u);
    return (unsigned short)(u >> 16);
}

__device__ __forceinline__ unsigned cvt_pk_bf16(float lo, float hi) {
    unsigned r;
    asm("v_cvt_pk_bf16_f32 %0, %1, %2" : "=v"(r) : "v"(lo), "v"(hi));
    return r;
}

__device__ __forceinline__ float bf2f(unsigned short u) {
    unsigned x = (unsigned)u << 16;
    return __builtin_bit_cast(float, x);
}

__device__ __forceinline__ bf16x8 pack8(const float* s) {
    union { unsigned u[4]; bf16x8 v; } r;
#pragma unroll
    for (int i = 0; i < 4; ++i) r.u[i] = cvt_pk_bf16(s[2 * i], s[2 * i + 1]);
    return r.v;
}

// async 16B global->LDS (dest wave-uniform; HW adds lane*16)
__device__ __forceinline__ void gload16(const void* g, void* l) {
    __builtin_amdgcn_global_load_lds(
        (const __attribute__((address_space(1))) unsigned*)g,
        (__attribute__((address_space(3))) unsigned*)l, 16, 0, 0);
}

// ---------------------------------------------------------------------------
// K0: Wt[k][d] bf16 = W[d][k] fp32; zero zpad.
// ---------------------------------------------------------------------------
__global__ __launch_bounds__(256) void k_wt(const float* __restrict__ W,
                                            unsigned short* __restrict__ Wt,
                                            float* __restrict__ zpad)
{
    int idx = blockIdx.x * 256 + threadIdx.x;   // 0..32767
    int k = idx >> 9, d = idx & 511;
    Wt[idx] = f2bf(W[(size_t)d * NK + k]);
    if (idx < 64) zpad[idx] = 0.f;
}

// ---------------------------------------------------------------------------
// K1: s = x.W + bias ; a = softmax_k(s) ; aT[b][k][n] bf16 ;
// a_sum_p[b][blk][k] (deterministic partials). grid (13,64), 4 waves.
// Tile 64n x 64k, BK=32, 16 steps, TRIPLE-buffered gload_lds staging:
// tile s+2 issued at iter s -> 2 iterations of HBM-latency cover.
// Queue at iter s: [T(s):3?, T(s+1):3, T(s+2):3] -> vmcnt(6); tail 3/0.
// LDS 36.9KB -> 4 blocks/CU (all 832 co-resident).
// ---------------------------------------------------------------------------
__global__ __launch_bounds__(256) void k_assign(
    const float* __restrict__ x, const unsigned short* __restrict__ Wt,
    const float* __restrict__ bias, unsigned short* __restrict__ aT,
    float* __restrict__ a_sum_p)
{
    // [0,24576) xbuf x3 (8KB each) | [24576,36864) wbuf x3 (4KB each)
    __shared__ __align__(16) char lds[36864];
    __shared__ float asw[4][64];

    const int t = threadIdx.x;
    const int w = t >> 6, l = t & 63, lr = l & 15, lg = l >> 4;
    const int b = blockIdx.y, n0 = blockIdx.x * 64;

    const float* xb = x + (size_t)b * NP * ND;

    auto STAGE = [&](int d0, int buf) {
        char* xdst = lds + buf * 8192 + w * 1024;
        char* wdst = lds + 24576 + buf * 4096 + w * 1024;
#pragma unroll
        for (int i = 0; i < 2; ++i) {            // x tile: [64n][8 chunks] fp32
            int flat = t + i * 256;
            int n = flat >> 3, c = flat & 7;
            int cs = c ^ (n & 7);
            int ng = n0 + n; if (ng >= NP) ng = NP - 1;   // dup rows discarded later
            gload16(xb + (size_t)ng * ND + d0 + cs * 4, xdst + i * 4096);
        }
        {                                         // Wt tile: [64k][4 chunks] bf16
            int k = t >> 2, c = t & 3;
            int cs = c ^ (k & 3);
            gload16(Wt + (size_t)k * ND + d0 + cs * 8, wdst);
        }
    };

    f32x4 acc[4] = {};
    STAGE(0, 0);
    STAGE(32, 1);
#pragma unroll
    for (int s = 0; s < 16; ++s) {
        if (s < 14)      { STAGE((s + 2) * 32, (s + 2) % 3); VMCNT(6); }
        else if (s == 14) { VMCNT(3); }
        else              { VMCNT(0); }
        BAR_HEAD();                              // buf[s%3] ready for all waves
        const char* xT = lds + (s % 3) * 8192;
        const char* wT = lds + 24576 + (s % 3) * 4096;
        const int nr = w * 16 + lr;
        const int cc = lg * 2;
        float av[8];
        *(f32x4*)&av[0] = *(const f32x4*)(xT + nr * 128 + ((cc ^ (nr & 7)) * 16));
        *(f32x4*)&av[4] = *(const f32x4*)(xT + nr * 128 + (((cc + 1) ^ (nr & 7)) * 16));
        bf16x8 af = pack8(av);
#pragma unroll
        for (int kf = 0; kf < 4; ++kf) {
            int kr = kf * 16 + lr;
            bf16x8 bfr = *(const bf16x8*)(wT + kr * 64 + ((lg ^ (kr & 3)) * 16));
            acc[kf] = __builtin_amdgcn_mfma_f32_16x16x32_bf16(af, bfr, acc[kf], 0, 0, 0);
        }
        BAR_TAIL();                              // drain LDS pipe, then barrier
    }

    // softmax over k: lane holds k = kf*16+lr, n = n0 + w*16 + lg*4 + r
    float pv[4][4];
    float part[4] = {0.f, 0.f, 0.f, 0.f};
    float bv[4];
#pragma unroll
    for (int kf = 0; kf < 4; ++kf) bv[kf] = bias[kf * 16 + lr];

#pragma unroll
    for (int r = 0; r < 4; ++r) {
        int n = n0 + w * 16 + lg * 4 + r;
        float sv[4];
        float m = -1e30f;
#pragma unroll
        for (int kf = 0; kf < 4; ++kf) { sv[kf] = acc[kf][r] + bv[kf]; m = fmaxf(m, sv[kf]); }
#pragma unroll
        for (int mask = 1; mask < 16; mask <<= 1)
            m = fmaxf(m, __shfl_xor(m, mask, 64));
        float sum = 0.f;
#pragma unroll
        for (int kf = 0; kf < 4; ++kf) { sv[kf] = __expf(sv[kf] - m); sum += sv[kf]; }
#pragma unroll
        for (int mask = 1; mask < 16; mask <<= 1)
            sum += __shfl_xor(sum, mask, 64);
        float inv = 1.0f / sum;
        bool valid = (n < NP);
#pragma unroll
        for (int kf = 0; kf < 4; ++kf) {
            pv[kf][r] = sv[kf] * inv;
            if (valid) part[kf] += pv[kf][r];
        }
    }
    // deterministic a_sum partial: reduce over lg (lane bits 4,5), per-wave slot
#pragma unroll
    for (int kf = 0; kf < 4; ++kf) {
        part[kf] += __shfl_xor(part[kf], 16, 64);
        part[kf] += __shfl_xor(part[kf], 32, 64);
    }
    if (lg == 0) {
#pragma unroll
        for (int kf = 0; kf < 4; ++kf) asw[w][kf * 16 + lr] = part[kf];
    }

    // bounce a -> [k][n] bf16 tile (aliases xbuf0: free after final compute)
    unsigned short* lb = (unsigned short*)lds;
    const int nl0 = w * 16 + lg * 4;
#pragma unroll
    for (int kf = 0; kf < 4; ++kf) {
        int krow = kf * 16 + lr;
#pragma unroll
        for (int rp = 0; rp < 2; ++rp) {
            unsigned v32 = cvt_pk_bf16(pv[kf][2 * rp], pv[kf][2 * rp + 1]);
            *(unsigned*)((char*)lb + krow * 128 +
                         ((nl0 * 2 + rp * 4) ^ ((krow & 7) << 4))) = v32;
        }
    }
    __syncthreads();
    for (int r2 = (t >> 3); r2 < 64; r2 += 32) {
        int n8 = (t & 7) * 8;
        if (n0 + n8 < NP) {
            int4 val = *(const int4*)((const char*)lb + r2 * 128 +
                                      ((n8 * 2) ^ ((r2 & 7) << 4)));
            *(int4*)(aT + ((size_t)b * NK + r2) * NP + n0 + n8) = val;
        }
    }
    if (t < 64) {
        float s = asw[0][t] + asw[1][t] + asw[2][t] + asw[3][t];  // fixed order
        a_sum_p[((size_t)b * 13 + blockIdx.x) * NK + t] = s;
    }
}

// ---------------------------------------------------------------------------
// K2: v[b][d][k] (bf16) = sum_n a[n][k]*x[n][d] + C[d][k]*a_sum[b][k]
// Depth-2 register pipeline for x (LOAD_B). ssq partials from fp32 acc
// (pre-rounding) -> k_scale. a_sum summed from 13 partials (L2-hot).
// grid flat 512: XCD of block = f&7 = b&7 -> batch b's v lands in that
// XCD's L2 (512KB/batch, 4MB/XCD).
// ---------------------------------------------------------------------------
__global__ __launch_bounds__(256) void k_vlad(
    const float* __restrict__ x, const unsigned short* __restrict__ aT,
    const float* __restrict__ Cm, const float* __restrict__ a_sum_p,
    unsigned short* __restrict__ v, const float* __restrict__ zpad,
    float* __restrict__ ssq_p)
{
    __shared__ __align__(16) char lds[16384];             // la dbuf 2 x 8KB
    __shared__ __align__(16) unsigned short lxT[8][1024]; // [wave*2+buf][16d x 64n]
    __shared__ float ssw[4][64];

    const int t = threadIdx.x;
    const int w = t >> 6, l = t & 63, lr = l & 15, lg = l >> 4;
    // XCD-bijective decode: same-batch d-blocks land on one XCD
    const int f = blockIdx.x;
    const int q = f >> 3;
    const int dgrp = q & 7;
    const int d0 = dgrp * 64;
    const int b  = (f & 7) + 8 * (q >> 3);
    const int np_ = l & 31, dq = l >> 5;

    const float* xb = x + (size_t)b * NP * ND;
    const unsigned short* ab = aT + (size_t)b * NK * NP;
    const float* xcol = xb + d0 + w * 16 + dq * 8;

    auto STAGE_A = [&](int n0, int buf) {
        char* dst = lds + buf * 8192 + w * 1024;
#pragma unroll
        for (int i = 0; i < 2; ++i) {
            int flat = t + i * 256;
            int k = flat >> 3, c = flat & 7;
            int cs = c ^ (k & 7);
            const void* src = (n0 + cs * 8 + 8 <= NP)
                              ? (const void*)(ab + (size_t)k * NP + n0 + cs * 8)
                              : (const void*)zpad;
            gload16(src, dst + i * 4096);
        }
    };

    float r0[2][8], r1[2][8];                    // two sets; indices compile-time
    auto LOAD_B = [&](int n0, int set) {
        int nlo = n0 + 2 * np_;
        int na = nlo < NP ? nlo : NP - 1;       // clamped rows multiply a=0
        int nb2 = nlo + 1 < NP ? nlo + 1 : NP - 1;
        *(f32x4*)&r0[set][0] = *(const f32x4*)(xcol + (size_t)na * ND);
        *(f32x4*)&r0[set][4] = *(const f32x4*)(xcol + (size_t)na * ND + 4);
        *(f32x4*)&r1[set][0] = *(const f32x4*)(xcol + (size_t)nb2 * ND);
        *(f32x4*)&r1[set][4] = *(const f32x4*)(xcol + (size_t)nb2 * ND + 4);
    };
    auto WRITE_B = [&](int buf, int set) {
        unsigned short* lt = lxT[w * 2 + buf];
#pragma unroll
        for (int jd = 0; jd < 8; ++jd) {
            int row = dq * 8 + jd;
            unsigned v32 = cvt_pk_bf16(r0[set][jd], r1[set][jd]);
            *(unsigned*)((char*)lt + row * 128 + ((np_ * 4) ^ ((row & 7) << 4))) = v32;
        }
    };

    f32x4 acc[4] = {};
    LOAD_B(0, 0);                                // tile 0 -> set0
    STAGE_A(0, 0);
    WRITE_B(0, 0);                               // auto-waits LB(0)
    LOAD_B(64, 1);                               // tile 1 -> set1
#pragma unroll
    for (int it = 0; it < 13; ++it) {
        const int n0 = it * 64;
        if (it <= 10) {
            STAGE_A(n0 + 64, (it + 1) & 1);
            LOAD_B(n0 + 128, it & 1);            // tile it+2 -> set[it&1]
            VMCNT(10);
        } else if (it == 11) {
            STAGE_A(n0 + 64, (it + 1) & 1);
            VMCNT(6);
        } else {
            VMCNT(0);
        }
        BAR_HEAD();                              // la[it&1] ready
        const char* la = lds + (it & 1) * 8192;
        const unsigned short* lt = lxT[w * 2 + (it & 1)];
#pragma unroll
        for (int kk = 0; kk < 2; ++kk) {
            bf16x8 bfr = *(const bf16x8*)((const char*)lt + lr * 128 +
                                          ((kk * 64 + lg * 16) ^ ((lr & 7) << 4)));
#pragma unroll
            for (int kf = 0; kf < 4; ++kf) {
                int kr = kf * 16 + lr;
                bf16x8 afr = *(const bf16x8*)(la + kr * 128 +
                                              (((kk * 4 + lg) ^ (kr & 7)) * 16));
                acc[kf] = __builtin_amdgcn_mfma_f32_16x16x32_bf16(afr, bfr, acc[kf], 0, 0, 0);
            }
        }
        if (it < 12) WRITE_B((it + 1) & 1, (it + 1) & 1);  // tile it+1 (1 iter old)
        BAR_TAIL();                              // drain LDS pipe, then barrier
    }

    // epilogue: d = d0+w*16+lr (col), k = kf*16+lg*4..+3 (rows)
    const int dcol = d0 + w * 16 + lr;
#pragma unroll
    for (int kf = 0; kf < 4; ++kf) {
        int kb = kf * 16 + lg * 4;
        f32x4 s4 = {};
#pragma unroll
        for (int c = 0; c < 13; ++c)            // fixed-order a_sum (L2-hot)
            s4 += *(const f32x4*)(a_sum_p + ((size_t)b * 13 + c) * NK + kb);
        f32x4 c4 = *(const f32x4*)(Cm + (size_t)dcol * NK + kb);
        f32x4 o = acc[kf] + c4 * s4;
        // v stored bf16 (8B/lane); ssq from fp32 o (pre-rounding)
        uint2 pk;
        pk.x = cvt_pk_bf16(o[0], o[1]);
        pk.y = cvt_pk_bf16(o[2], o[3]);
        *(uint2*)(v + ((size_t)b * ND + dcol) * NK + kb) = pk;
        f32x4 qq = o * o;
#pragma unroll
        for (int m = 1; m < 16; m <<= 1) {
            qq[0] += __shfl_xor(qq[0], m, 64);
            qq[1] += __shfl_xor(qq[1], m, 64);
            qq[2] += __shfl_xor(qq[2], m, 64);
            qq[3] += __shfl_xor(qq[3], m, 64);
        }
        if (lr == 0) {
            ssw[w][kb + 0] = qq[0]; ssw[w][kb + 1] = qq[1];
            ssw[w][kb + 2] = qq[2]; ssw[w][kb + 3] = qq[3];
        }
    }
    __syncthreads();
    if (t < 64) {
        float s = ssw[0][t] + ssw[1][t] + ssw[2][t] + ssw[3][t];  // fixed order
        ssq_p[((size_t)b * 8 + dgrp) * NK + t] = s;
    }
}

// ---------------------------------------------------------------------------
// K3: scale-only normalize. grid 512, XCD-ALIGNED with k_vlad: block f ->
// XCD f&7 = b&7, matching where k_vlad left batch b's v in L2.
// Reads v bf16, writes out fp32.
// ---------------------------------------------------------------------------
__global__ __launch_bounds__(256) void k_scale(
    const unsigned short* __restrict__ v, const float* __restrict__ ssq_p,
    float* __restrict__ out)
{
    __shared__ float scl[64];
    const int t = threadIdx.x;
    const int f = blockIdx.x;
    const int b  = (f & 7) + 8 * (f >> 6);      // XCD = f&7 = b&7 (matches k_vlad)
    const int dg = (f >> 3) & 7;

    if (t < 64) {
        float tot = 0.f;
#pragma unroll
        for (int c = 0; c < 8; ++c) tot += ssq_p[((size_t)b * 8 + c) * NK + t];
        float cc = tot / (tot + EPS_F);
        float g = cc;
#pragma unroll
        for (int mask = 1; mask < 64; mask <<= 1)
            g += __shfl_xor(g, mask, 64);
        scl[t] = 1.0f / (sqrtf(tot + EPS_F) * sqrtf(g + EPS_F));
    }
    __syncthreads();

    const unsigned short* vb = v + ((size_t)b * ND + dg * 64) * NK;
    float* ob = out + ((size_t)b * ND + dg * 64) * NK;
    f32x4 sc4 = *(const f32x4*)(&scl[(t & 15) * 4]);   // thread's k-quad fixed
#pragma unroll
    for (int i = 0; i < 4; ++i) {
        int idx = i * 256 + t;                  // quad index; idx&15 == t&15
        int row = idx >> 4;
        ushort4 pk = *(const ushort4*)(vb + row * NK + (t & 15) * 4);
        f32x4 val = { bf2f(pk.x), bf2f(pk.y), bf2f(pk.z), bf2f(pk.w) };
        *(f32x4*)(ob + row * NK + (t & 15) * 4) = val * sc4;
    }
}

// ---------------------------------------------------------------------------
extern "C" void kernel_launch(void* const* d_in, const int* in_sizes, int n_in,
                              void* d_out, int out_size, void* d_ws, size_t ws_size,
                              hipStream_t stream)
{
    const float* x    = (const float*)d_in[0];
    const float* Wm   = (const float*)d_in[1];
    const float* bias = (const float*)d_in[2];
    const float* Cm   = (const float*)d_in[3];
    float* out = (float*)d_out;

    char* ws = (char*)d_ws;
    unsigned short* aT = (unsigned short*)ws;                 // 6,422,528 B
    char* p = ws + (size_t)NB * NK * NP * 2;
    float* a_sum_p = (float*)p;                               // 212,992 B
    p += (size_t)NB * 13 * NK * 4;
    unsigned short* v = (unsigned short*)p;                   // 4,194,304 B (bf16)
    p += (size_t)NB * ND * NK * 2;
    unsigned short* Wt = (unsigned short*)p;                  // 65,536 B
    p += (size_t)NK * ND * 2;
    float* zpad = (float*)p;                                  // 256 B
    p += 256;
    float* ssq_p = (float*)p;                                 // 131,072 B

    hipLaunchKernelGGL(k_wt, dim3(128), dim3(256), 0, stream, Wm, Wt, zpad);
    dim3 g1((NP + 63) / 64, NB);
    hipLaunchKernelGGL(k_assign, g1, dim3(256), 0, stream, x, Wt, bias, aT, a_sum_p);
    hipLaunchKernelGGL(k_vlad, dim3(512), dim3(256), 0, stream, x, aT, Cm, a_sum_p, v, zpad, ssq_p);
    hipLaunchKernelGGL(k_scale, dim3(512), dim3(256), 0, stream, v, ssq_p, out);
}